// Round 4
// baseline (1505.634 us; speedup 1.0000x reference)
//
#include <hip/hip_runtime.h>

#define NNODES 50000
#define NEDGES 500000
#define NBINS  (NNODES * 4)

// wf fp32 arena offsets (in floats)
#define WF_W1    0
#define WF_B1    4096
#define WF_W2    4160
#define WF_B2    8256
#define WF_W3    8320
#define WF_B3    8384
#define WF_SSC   8385
#define WF_STC   9409
#define WF_BIAS  10433
#define WF_GAMMA 10689
#define WF_BETA  10945
#define WF_TOT   11201

typedef __attribute__((ext_vector_type(8))) short short8;
typedef __attribute__((ext_vector_type(4))) float floatx4;
typedef __attribute__((ext_vector_type(4))) unsigned int uint4v;

__device__ __forceinline__ float bf2f(unsigned short u) {
    return __uint_as_float(((unsigned)u) << 16);
}
__device__ __forceinline__ unsigned f2bf(float f) {
    unsigned u = __float_as_uint(f);
    u += 0x7fffu + ((u >> 16) & 1u);
    return u >> 16;
}
__device__ __forceinline__ float bflo(unsigned u) { return __uint_as_float(u << 16); }
__device__ __forceinline__ float bfhi(unsigned u) { return __uint_as_float(u & 0xffff0000u); }
__device__ __forceinline__ int clampi(int v, int hi) { return v < 0 ? 0 : (v > hi ? hi : v); }

// ---------------------------------------------------------------------------
// dtype probe: if the u16 stream of x contains many huge "bf16" decodes, the
// underlying data is fp32 (mantissa halves have random exponents). flag=1: fp32
// ---------------------------------------------------------------------------
__global__ __launch_bounds__(256) void probe_k(const unsigned short* __restrict__ xs,
                                               unsigned* __restrict__ flag) {
    __shared__ unsigned cnt;
    if (threadIdx.x == 0) cnt = 0;
    __syncthreads();
    unsigned local = 0;
    for (int i = threadIdx.x; i < 8192; i += 256) {
        float v = bf2f(xs[i]);
        if (!(fabsf(v) < 1e10f)) local++;   // catches huge/Inf/NaN decodes
    }
    atomicAdd(&cnt, local);
    __syncthreads();
    if (threadIdx.x == 0) *flag = (cnt > 256u) ? 1u : 0u;
}

// ---------------------------------------------------------------------------
// polymorphic small-param conversion into fp32 arena
// ---------------------------------------------------------------------------
__device__ __forceinline__ float ldf(const void* p, int i, bool f32) {
    return f32 ? ((const float*)p)[i] : bf2f(((const unsigned short*)p)[i]);
}

__global__ __launch_bounds__(1024) void wconv_k(const void* W1, const void* b1,
                                                const void* W2, const void* b2,
                                                const void* W3, const void* b3,
                                                const void* ssc, const void* stc,
                                                const void* bias, const void* gamma,
                                                const void* beta,
                                                const unsigned* __restrict__ flag,
                                                float* __restrict__ wf) {
    bool f32 = (*flag != 0u);
    for (int i = threadIdx.x; i < WF_TOT; i += 1024) {
        float v;
        if (i < WF_B1)          v = ldf(W1, i - WF_W1, f32);
        else if (i < WF_W2)     v = ldf(b1, i - WF_B1, f32);
        else if (i < WF_B2)     v = ldf(W2, i - WF_W2, f32);
        else if (i < WF_W3)     v = ldf(b2, i - WF_B2, f32);
        else if (i < WF_B3)     v = ldf(W3, i - WF_W3, f32);
        else if (i < WF_SSC)    v = ldf(b3, i - WF_B3, f32);
        else if (i < WF_STC)    v = ldf(ssc, i - WF_SSC, f32);
        else if (i < WF_BIAS)   v = ldf(stc, i - WF_STC, f32);
        else if (i < WF_GAMMA)  v = ldf(bias, i - WF_BIAS, f32);
        else if (i < WF_BETA)   v = ldf(gamma, i - WF_GAMMA, f32);
        else                    v = ldf(beta, i - WF_BETA, f32);
        wf[i] = v;
    }
}

// ---------------------------------------------------------------------------
// polymorphic MFMA fragment load: 8 contiguous K elements at elem index idx
// ---------------------------------------------------------------------------
__device__ __forceinline__ short8 ldfrag(const void* P, size_t idx, bool f32) {
    if (f32) {
        const float* pf = (const float*)P;
        floatx4 a = *(const floatx4*)(pf + idx);
        floatx4 b = *(const floatx4*)(pf + idx + 4);
        short8 r;
        r[0] = (short)f2bf(a[0]); r[1] = (short)f2bf(a[1]);
        r[2] = (short)f2bf(a[2]); r[3] = (short)f2bf(a[3]);
        r[4] = (short)f2bf(b[0]); r[5] = (short)f2bf(b[1]);
        r[6] = (short)f2bf(b[2]); r[7] = (short)f2bf(b[3]);
        return r;
    }
    return *(const short8*)((const unsigned short*)P + idx);
}

// ---------------------------------------------------------------------------
// GEMM: C[m, j] = sum_k A[m,k] * B[j,k]  (A, B dtype per flag; C:
// c_poly=0 -> always bf16 (internal), c_poly=1 -> dtype per flag (d_out))
// ---------------------------------------------------------------------------
__global__ __launch_bounds__(256) void gemm_bt(const void* __restrict__ A,
                                               const void* __restrict__ B,
                                               unsigned short* __restrict__ C16,
                                               float* __restrict__ C32,
                                               int M, int Nout, int K,
                                               const unsigned* __restrict__ flag,
                                               int c_poly) {
    const bool f32 = (*flag != 0u);
    const bool cf32 = f32 && (c_poly != 0);
    const int wave = threadIdx.x >> 6;
    const int lane = threadIdx.x & 63;
    const int l15  = lane & 15;
    const int q    = lane >> 4;
    const int m0   = blockIdx.x * 256 + wave * 64;
    const int n0   = blockIdx.y * 64;

    floatx4 acc[4][4];
#pragma unroll
    for (int i = 0; i < 4; i++)
#pragma unroll
        for (int j = 0; j < 4; j++) acc[i][j] = (floatx4){0.f, 0.f, 0.f, 0.f};

    for (int kc = 0; kc < K; kc += 32) {
        short8 af[4], bfr[4];
#pragma unroll
        for (int mt = 0; mt < 4; mt++) {
            int row = m0 + mt * 16 + l15;
            row = row < M ? row : M - 1;
            af[mt] = ldfrag(A, (size_t)row * K + kc + q * 8, f32);
        }
#pragma unroll
        for (int nt = 0; nt < 4; nt++) {
            int col = n0 + nt * 16 + l15;
            bfr[nt] = ldfrag(B, (size_t)col * K + kc + q * 8, f32);
        }
#pragma unroll
        for (int mt = 0; mt < 4; mt++)
#pragma unroll
            for (int nt = 0; nt < 4; nt++)
                acc[mt][nt] = __builtin_amdgcn_mfma_f32_16x16x32_bf16(af[mt], bfr[nt],
                                                                     acc[mt][nt], 0, 0, 0);
    }

#pragma unroll
    for (int mt = 0; mt < 4; mt++)
#pragma unroll
        for (int nt = 0; nt < 4; nt++)
#pragma unroll
            for (int r = 0; r < 4; r++) {
                int row = m0 + mt * 16 + q * 4 + r;
                int col = n0 + nt * 16 + l15;
                if (row < M) {
                    size_t idx = (size_t)row * Nout + col;
                    float v = acc[mt][nt][r];
                    if (cf32) C32[idx] = v;
                    else      C16[idx] = (unsigned short)f2bf(v);
                }
            }
}

// ---------------------------------------------------------------------------
// per (n,h,r): s_src / s_trg dots (proj internal bf16, score vecs fp32 arena)
// ---------------------------------------------------------------------------
__global__ __launch_bounds__(256) void scores_k(const unsigned short* __restrict__ proj,
                                                const float* __restrict__ wf,
                                                float* __restrict__ s_src,
                                                float* __restrict__ s_trg, int NC) {
    int tid = blockIdx.x * 256 + threadIdx.x;
    if (tid >= NC) return;
    int cell = tid & 15;  // h*4 + r
    const uint4v* p  = (const uint4v*)(proj + (size_t)tid * 64);
    const float* av  = wf + WF_SSC + cell * 64;
    const float* bv  = wf + WF_STC + cell * 64;
    float accA = 0.f, accB = 0.f;
#pragma unroll
    for (int c = 0; c < 8; c++) {
        uint4v pv = p[c];
#pragma unroll
        for (int j = 0; j < 4; j++) {
            int k = c * 8 + j * 2;
            float p0 = bflo(pv[j]), p1 = bfhi(pv[j]);
            accA = fmaf(p0, av[k], accA);
            accA = fmaf(p1, av[k + 1], accA);
            accB = fmaf(p0, bv[k], accB);
            accB = fmaf(p1, bv[k + 1], accB);
        }
    }
    s_src[tid] = accA;
    s_trg[tid] = accB;
}

// ---------------------------------------------------------------------------
// CSR build: count -> scan (writes offsets AND cursor) -> fill
// ---------------------------------------------------------------------------
__global__ __launch_bounds__(256) void count_k(const int* __restrict__ trg,
                                               const int* __restrict__ rel,
                                               unsigned* __restrict__ counts, int E) {
    int e = blockIdx.x * 256 + threadIdx.x;
    if (e >= E) return;
    int g = clampi(trg[e], NNODES - 1);
    int r = clampi(rel[e], 3);
    atomicAdd(&counts[g * 4 + r], 1u);
}

__global__ __launch_bounds__(1024) void scan_k(const unsigned* __restrict__ counts,
                                               unsigned* __restrict__ offsets,
                                               unsigned* __restrict__ cursor) {
    const int CH = 196;  // 1024*196 = 200704 >= 200000
    __shared__ unsigned ps[1024];
    int t = threadIdx.x;
    int b0 = t * CH;
    unsigned local = 0;
    for (int i = 0; i < CH; i++) {
        int b = b0 + i;
        if (b < NBINS) local += counts[b];
    }
    ps[t] = local;
    __syncthreads();
    for (int off = 1; off < 1024; off <<= 1) {
        unsigned v = (t >= off) ? ps[t - off] : 0u;
        __syncthreads();
        ps[t] += v;
        __syncthreads();
    }
    unsigned run = (t == 0) ? 0u : ps[t - 1];
    for (int i = 0; i < CH; i++) {
        int b = b0 + i;
        if (b < NBINS) {
            offsets[b] = run;
            cursor[b] = run;
            run += counts[b];
        }
    }
    if (t == 1023) offsets[NBINS] = ps[1023];
}

__global__ __launch_bounds__(256) void fill_k(const int* __restrict__ src,
                                              const int* __restrict__ trg,
                                              const int* __restrict__ rel,
                                              const float* __restrict__ s_src,
                                              const float* __restrict__ s_trg,
                                              unsigned* __restrict__ cursor,
                                              unsigned* __restrict__ esrc,
                                              floatx4* __restrict__ eexp, int E) {
    int e = blockIdx.x * 256 + threadIdx.x;
    if (e >= E) return;
    int s = clampi(src[e], NNODES - 1);
    int g = clampi(trg[e], NNODES - 1);
    int r = clampi(rel[e], 3);
    unsigned pos = atomicAdd(&cursor[g * 4 + r], 1u);
    if (pos >= (unsigned)E) pos = E - 1;  // cannot happen; insurance
    esrc[pos] = (unsigned)s;
    floatx4 v;
#pragma unroll
    for (int h = 0; h < 4; h++) {
        float val = s_src[s * 16 + h * 4 + r] + s_trg[g * 16 + h * 4 + r];
        val = val > 0.f ? val : 0.2f * val;   // leaky_relu(0.2)
        v[h] = expf(val);
    }
    eexp[pos] = v;
}

// ---------------------------------------------------------------------------
// fused per-row (n,h,r): CSR gather-aggregate (normalized) -> agg row (bf16)
// + MLP (fp32 arena weights, vectorized) -> mish score
// ---------------------------------------------------------------------------
__global__ __launch_bounds__(256) void rowagg_mlp_k(const unsigned* __restrict__ offsets,
                                                    const unsigned* __restrict__ esrc,
                                                    const floatx4* __restrict__ eexp,
                                                    const unsigned short* __restrict__ proj,
                                                    const float* __restrict__ wf,
                                                    unsigned short* __restrict__ agg,
                                                    float* __restrict__ sc) {
    int row = blockIdx.x * 256 + threadIdx.x;  // row = n*16 + h*4 + r
    int n = row >> 4, h = (row >> 2) & 3, r = row & 3;
    int bin = n * 4 + r;
    unsigned beg = offsets[bin], end = offsets[bin + 1];

    float a[64];
#pragma unroll
    for (int k = 0; k < 64; k++) a[k] = 0.f;
    float den = 0.f;

    for (unsigned i = beg; i < end; i++) {
        int s = clampi((int)esrc[i], NNODES - 1);
        floatx4 pe = eexp[i];
        float p = pe[h];
        den += p;
        const uint4v* prow = (const uint4v*)(proj + ((size_t)(s * 4 + h) * 4 + r) * 64);
#pragma unroll
        for (int c = 0; c < 8; c++) {
            uint4v v = prow[c];
#pragma unroll
            for (int j = 0; j < 4; j++) {
                a[c * 8 + j * 2]     = fmaf(p, bflo(v[j]), a[c * 8 + j * 2]);
                a[c * 8 + j * 2 + 1] = fmaf(p, bfhi(v[j]), a[c * 8 + j * 2 + 1]);
            }
        }
    }
    float inv = 1.f / (den + 1e-16f);
#pragma unroll
    for (int k = 0; k < 64; k++) a[k] *= inv;

    // store agg row as bf16, layout (n, r, h, f)
    uint4v* arow = (uint4v*)(agg + ((size_t)(n * 4 + r) * 4 + h) * 64);
#pragma unroll
    for (int c = 0; c < 8; c++) {
        uint4v o;
#pragma unroll
        for (int j = 0; j < 4; j++)
            o[j] = f2bf(a[c * 8 + j * 2]) | (f2bf(a[c * 8 + j * 2 + 1]) << 16);
        arow[c] = o;
    }

    const float* W1f = wf + WF_W1;
    const float* b1f = wf + WF_B1;
    const float* W2f = wf + WF_W2;
    const float* b2f = wf + WF_B2;
    const float* W3f = wf + WF_W3;
    const float* b3f = wf + WF_B3;

    float b[64];
#pragma unroll
    for (int i = 0; i < 64; i++) {
        float acc = b1f[i];
        const floatx4* w = (const floatx4*)(W1f + i * 64);
#pragma unroll
        for (int c = 0; c < 16; c++) {
            floatx4 wv = w[c];
            acc = fmaf(wv[0], a[c * 4 + 0], acc);
            acc = fmaf(wv[1], a[c * 4 + 1], acc);
            acc = fmaf(wv[2], a[c * 4 + 2], acc);
            acc = fmaf(wv[3], a[c * 4 + 3], acc);
        }
        b[i] = fmaxf(acc, 0.f);
    }
#pragma unroll
    for (int i = 0; i < 64; i++) {
        float acc = b2f[i];
        const floatx4* w = (const floatx4*)(W2f + i * 64);
#pragma unroll
        for (int c = 0; c < 16; c++) {
            floatx4 wv = w[c];
            acc = fmaf(wv[0], b[c * 4 + 0], acc);
            acc = fmaf(wv[1], b[c * 4 + 1], acc);
            acc = fmaf(wv[2], b[c * 4 + 2], acc);
            acc = fmaf(wv[3], b[c * 4 + 3], acc);
        }
        a[i] = fmaxf(acc, 0.f);
    }
    float acc = b3f[0];
    const floatx4* w3 = (const floatx4*)W3f;
#pragma unroll
    for (int c = 0; c < 16; c++) {
        floatx4 wv = w3[c];
        acc = fmaf(wv[0], a[c * 4 + 0], acc);
        acc = fmaf(wv[1], a[c * 4 + 1], acc);
        acc = fmaf(wv[2], a[c * 4 + 2], acc);
        acc = fmaf(wv[3], a[c * 4 + 3], acc);
    }

    // stable softplus; mish = x * tanh(softplus(x))
    float sp = fmaxf(acc, 0.f) + log1pf(expf(-fabsf(acc)));
    sc[row] = acc * tanhf(sp);
}

// ---------------------------------------------------------------------------
// final: softmax over r, weighted sum, +skip(in d_out)+bias, ELU, LayerNorm
// ---------------------------------------------------------------------------
__global__ __launch_bounds__(256) void final_k(const unsigned short* __restrict__ agg,
                                               const float* __restrict__ sc,
                                               const float* __restrict__ wf,
                                               const unsigned* __restrict__ flag,
                                               unsigned short* __restrict__ out16,
                                               float* __restrict__ out32) {
    const bool f32 = (*flag != 0u);
    int n = blockIdx.x, t = threadIdx.x;
    int h = t >> 6, f = t & 63;
    float s0 = sc[n * 16 + h * 4 + 0];
    float s1 = sc[n * 16 + h * 4 + 1];
    float s2 = sc[n * 16 + h * 4 + 2];
    float s3 = sc[n * 16 + h * 4 + 3];
    float mx = fmaxf(fmaxf(s0, s1), fmaxf(s2, s3));
    float e0 = expf(s0 - mx), e1 = expf(s1 - mx), e2 = expf(s2 - mx), e3 = expf(s3 - mx);
    float inv = 1.f / (e0 + e1 + e2 + e3);
    size_t base = (size_t)n * 1024 + h * 64 + f;       // agg (n, r, h, f)
    float a0 = bf2f(agg[base]);
    float a1 = bf2f(agg[base + 256]);
    float a2 = bf2f(agg[base + 512]);
    float a3 = bf2f(agg[base + 768]);
    float v = (e0 * a0 + e1 * a1 + e2 * a2 + e3 * a3) * inv;
    size_t oidx = (size_t)n * 256 + t;
    float skipv = f32 ? out32[oidx] : bf2f(out16[oidx]);  // skip staged in d_out
    v += skipv + wf[WF_BIAS + t];
    v = v > 0.f ? v : expm1f(v);

    float s = v, q = v * v;
#pragma unroll
    for (int o = 1; o < 64; o <<= 1) {
        s += __shfl_xor(s, o);
        q += __shfl_xor(q, o);
    }
    __shared__ float red[8];
    __shared__ float stat[2];
    int wv = t >> 6, ln = t & 63;
    if (ln == 0) { red[wv] = s; red[4 + wv] = q; }
    __syncthreads();
    if (t == 0) {
        float S = red[0] + red[1] + red[2] + red[3];
        float Q = red[4] + red[5] + red[6] + red[7];
        float mu = S * (1.f / 256.f);
        float var = fmaxf(Q * (1.f / 256.f) - mu * mu, 0.f);
        stat[0] = mu;
        stat[1] = rsqrtf(var + 1e-5f);
    }
    __syncthreads();
    float o = (v - stat[0]) * stat[1] * wf[WF_GAMMA + t] + wf[WF_BETA + t];
    if (f32) out32[oidx] = o;
    else     out16[oidx] = (unsigned short)f2bf(o);
}

// ---------------------------------------------------------------------------
// workspace layout (bytes), total ~226.85 MB:
//   proj    bf16 (N,NH,NR,F)   0           .. 102,400,000
//   agg     bf16 (N,NR,NH,F)   102,400,000 .. 204,800,000
//   s_src   f32  (N,16)        204,800,000 .. 208,000,000
//   s_trg   f32  (N,16)        208,000,000 .. 211,200,000
//   eexp    f32x4 (E)          211,200,000 .. 219,200,000
//   esrc    u32  (E)           219,200,000 .. 221,200,000
//   counts  u32  (NBINS)       221,200,000 .. 222,000,000
//   offsets u32  (NBINS+1)     222,000,000 .. 222,800,016
//   cursor  u32  (NBINS)       222,800,016 .. 223,600,016
//   sc      f32  (N,16)        223,600,016 .. 226,800,016
//   wf      f32  (WF_TOT)      226,800,016 .. 226,844,820
//   flag    u32                226,844,824 .. 226,844,828
// ---------------------------------------------------------------------------
extern "C" void kernel_launch(void* const* d_in, const int* in_sizes, int n_in,
                              void* d_out, int out_size, void* d_ws, size_t ws_size,
                              hipStream_t stream) {
    if (ws_size < 226900000) return;  // clean diagnostic failure (absmax ~5.875)

    const void* x      = d_in[0];
    const int* src     = (const int*)d_in[1];
    const int* trg     = (const int*)d_in[2];
    const int* rel     = (const int*)d_in[3];
    const void* W_proj = d_in[5];
    const void* ssc    = d_in[6];
    const void* stc    = d_in[7];
    const void* W1     = d_in[8];
    const void* b1     = d_in[9];
    const void* W2     = d_in[10];
    const void* b2     = d_in[11];
    const void* W3     = d_in[12];
    const void* b3     = d_in[13];
    const void* W_skip = d_in[14];
    const void* bias   = d_in[15];
    const void* gamma  = d_in[16];
    const void* beta   = d_in[17];
    unsigned short* out16 = (unsigned short*)d_out;
    float* out32          = (float*)d_out;

    char* w = (char*)d_ws;
    unsigned short* proj = (unsigned short*)(w + 0);
    unsigned short* agg  = (unsigned short*)(w + 102400000);
    float* s_src         = (float*)(w + 204800000);
    float* s_trg         = (float*)(w + 208000000);
    floatx4* eexp        = (floatx4*)(w + 211200000);
    unsigned* esrc       = (unsigned*)(w + 219200000);
    unsigned* counts     = (unsigned*)(w + 221200000);
    unsigned* offsets    = (unsigned*)(w + 222000000);
    unsigned* cursor     = (unsigned*)(w + 222800016);
    float* sc            = (float*)(w + 223600016);
    float* wf            = (float*)(w + 226800016);
    unsigned* flag       = (unsigned*)(w + 226844824);

    hipMemsetAsync(counts, 0, NBINS * 4, stream);

    probe_k<<<1, 256, 0, stream>>>((const unsigned short*)x, flag);
    wconv_k<<<1, 1024, 0, stream>>>(W1, b1, W2, b2, W3, b3, ssc, stc, bias, gamma, beta,
                                    flag, wf);
    // proj = x @ W_proj^T (internal bf16)
    gemm_bt<<<dim3(196, 16), 256, 0, stream>>>(x, W_proj, proj, nullptr,
                                               NNODES, 1024, 256, flag, 0);
    // skip = x @ W_skip^T -> d_out (dtype per flag)
    gemm_bt<<<dim3(196, 4), 256, 0, stream>>>(x, W_skip, out16, out32,
                                              NNODES, 256, 256, flag, 1);
    scores_k<<<3125, 256, 0, stream>>>(proj, wf, s_src, s_trg, NNODES * 16);
    count_k<<<1954, 256, 0, stream>>>(trg, rel, counts, NEDGES);
    scan_k<<<1, 1024, 0, stream>>>(counts, offsets, cursor);
    fill_k<<<1954, 256, 0, stream>>>(src, trg, rel, s_src, s_trg, cursor, esrc, eexp, NEDGES);
    rowagg_mlp_k<<<3125, 256, 0, stream>>>(offsets, esrc, eexp, proj, wf, agg, sc);
    final_k<<<NNODES, 256, 0, stream>>>(agg, sc, wf, flag, out16, out32);
}

// Round 5
// 1012.408 us; speedup vs baseline: 1.4872x; 1.4872x over previous
//
#include <hip/hip_runtime.h>

#define NNODES 50000
#define NEDGES 500000
#define NBINS  (NNODES * 4)
#define NSCANB 196   // ceil(NBINS / 1024)

// wf fp32 arena offsets (in floats)
#define WF_W1    0
#define WF_B1    4096
#define WF_W2    4160
#define WF_B2    8256
#define WF_W3    8320
#define WF_B3    8384
#define WF_SSC   8385
#define WF_STC   9409
#define WF_BIAS  10433
#define WF_GAMMA 10689
#define WF_BETA  10945
#define WF_TOT   11201

typedef __attribute__((ext_vector_type(8))) short short8;
typedef __attribute__((ext_vector_type(4))) float floatx4;
typedef __attribute__((ext_vector_type(4))) unsigned int uint4v;

__device__ __forceinline__ float bf2f(unsigned short u) {
    return __uint_as_float(((unsigned)u) << 16);
}
__device__ __forceinline__ unsigned f2bf(float f) {
    unsigned u = __float_as_uint(f);
    u += 0x7fffu + ((u >> 16) & 1u);
    return u >> 16;
}
__device__ __forceinline__ float bflo(unsigned u) { return __uint_as_float(u << 16); }
__device__ __forceinline__ float bfhi(unsigned u) { return __uint_as_float(u & 0xffff0000u); }
__device__ __forceinline__ int clampi(int v, int hi) { return v < 0 ? 0 : (v > hi ? hi : v); }

// ---------------------------------------------------------------------------
// dtype probe: if the u16 stream of x contains many huge "bf16" decodes, the
// underlying data is fp32 (mantissa halves have random exponents). flag=1: fp32
// ---------------------------------------------------------------------------
__global__ __launch_bounds__(256) void probe_k(const unsigned short* __restrict__ xs,
                                               unsigned* __restrict__ flag) {
    __shared__ unsigned cnt;
    if (threadIdx.x == 0) cnt = 0;
    __syncthreads();
    unsigned local = 0;
    for (int i = threadIdx.x; i < 8192; i += 256) {
        float v = bf2f(xs[i]);
        if (!(fabsf(v) < 1e10f)) local++;   // catches huge/Inf/NaN decodes
    }
    atomicAdd(&cnt, local);
    __syncthreads();
    if (threadIdx.x == 0) *flag = (cnt > 256u) ? 1u : 0u;
}

// ---------------------------------------------------------------------------
// polymorphic small-param conversion into fp32 arena
// ---------------------------------------------------------------------------
__device__ __forceinline__ float ldf(const void* p, int i, bool f32) {
    return f32 ? ((const float*)p)[i] : bf2f(((const unsigned short*)p)[i]);
}

__global__ __launch_bounds__(1024) void wconv_k(const void* W1, const void* b1,
                                                const void* W2, const void* b2,
                                                const void* W3, const void* b3,
                                                const void* ssc, const void* stc,
                                                const void* bias, const void* gamma,
                                                const void* beta,
                                                const unsigned* __restrict__ flag,
                                                float* __restrict__ wf) {
    bool f32 = (*flag != 0u);
    for (int i = threadIdx.x; i < WF_TOT; i += 1024) {
        float v;
        if (i < WF_B1)          v = ldf(W1, i - WF_W1, f32);
        else if (i < WF_W2)     v = ldf(b1, i - WF_B1, f32);
        else if (i < WF_B2)     v = ldf(W2, i - WF_W2, f32);
        else if (i < WF_W3)     v = ldf(b2, i - WF_B2, f32);
        else if (i < WF_B3)     v = ldf(W3, i - WF_W3, f32);
        else if (i < WF_SSC)    v = ldf(b3, i - WF_B3, f32);
        else if (i < WF_STC)    v = ldf(ssc, i - WF_SSC, f32);
        else if (i < WF_BIAS)   v = ldf(stc, i - WF_STC, f32);
        else if (i < WF_GAMMA)  v = ldf(bias, i - WF_BIAS, f32);
        else if (i < WF_BETA)   v = ldf(gamma, i - WF_GAMMA, f32);
        else                    v = ldf(beta, i - WF_BETA, f32);
        wf[i] = v;
    }
}

// ---------------------------------------------------------------------------
// polymorphic MFMA fragment load: 8 contiguous K elements at elem index idx
// ---------------------------------------------------------------------------
__device__ __forceinline__ short8 ldfrag(const void* P, size_t idx, bool f32) {
    if (f32) {
        const float* pf = (const float*)P;
        floatx4 a = *(const floatx4*)(pf + idx);
        floatx4 b = *(const floatx4*)(pf + idx + 4);
        short8 r;
        r[0] = (short)f2bf(a[0]); r[1] = (short)f2bf(a[1]);
        r[2] = (short)f2bf(a[2]); r[3] = (short)f2bf(a[3]);
        r[4] = (short)f2bf(b[0]); r[5] = (short)f2bf(b[1]);
        r[6] = (short)f2bf(b[2]); r[7] = (short)f2bf(b[3]);
        return r;
    }
    return *(const short8*)((const unsigned short*)P + idx);
}

// ---------------------------------------------------------------------------
// GEMM: C[m, j] = sum_k A[m,k] * B[j,k]  (A, B dtype per flag; C:
// c_poly=0 -> always bf16 (internal), c_poly=1 -> dtype per flag (d_out))
// ---------------------------------------------------------------------------
__global__ __launch_bounds__(256) void gemm_bt(const void* __restrict__ A,
                                               const void* __restrict__ B,
                                               unsigned short* __restrict__ C16,
                                               float* __restrict__ C32,
                                               int M, int Nout, int K,
                                               const unsigned* __restrict__ flag,
                                               int c_poly) {
    const bool f32 = (*flag != 0u);
    const bool cf32 = f32 && (c_poly != 0);
    const int wave = threadIdx.x >> 6;
    const int lane = threadIdx.x & 63;
    const int l15  = lane & 15;
    const int q    = lane >> 4;
    const int m0   = blockIdx.x * 256 + wave * 64;
    const int n0   = blockIdx.y * 64;

    floatx4 acc[4][4];
#pragma unroll
    for (int i = 0; i < 4; i++)
#pragma unroll
        for (int j = 0; j < 4; j++) acc[i][j] = (floatx4){0.f, 0.f, 0.f, 0.f};

    for (int kc = 0; kc < K; kc += 32) {
        short8 af[4], bfr[4];
#pragma unroll
        for (int mt = 0; mt < 4; mt++) {
            int row = m0 + mt * 16 + l15;
            row = row < M ? row : M - 1;
            af[mt] = ldfrag(A, (size_t)row * K + kc + q * 8, f32);
        }
#pragma unroll
        for (int nt = 0; nt < 4; nt++) {
            int col = n0 + nt * 16 + l15;
            bfr[nt] = ldfrag(B, (size_t)col * K + kc + q * 8, f32);
        }
#pragma unroll
        for (int mt = 0; mt < 4; mt++)
#pragma unroll
            for (int nt = 0; nt < 4; nt++)
                acc[mt][nt] = __builtin_amdgcn_mfma_f32_16x16x32_bf16(af[mt], bfr[nt],
                                                                     acc[mt][nt], 0, 0, 0);
    }

#pragma unroll
    for (int mt = 0; mt < 4; mt++)
#pragma unroll
        for (int nt = 0; nt < 4; nt++)
#pragma unroll
            for (int r = 0; r < 4; r++) {
                int row = m0 + mt * 16 + q * 4 + r;
                int col = n0 + nt * 16 + l15;
                if (row < M) {
                    size_t idx = (size_t)row * Nout + col;
                    float v = acc[mt][nt][r];
                    if (cf32) C32[idx] = v;
                    else      C16[idx] = (unsigned short)f2bf(v);
                }
            }
}

// ---------------------------------------------------------------------------
// per (n,h,r): s_src / s_trg dots (proj internal bf16, score vecs fp32 arena)
// ---------------------------------------------------------------------------
__global__ __launch_bounds__(256) void scores_k(const unsigned short* __restrict__ proj,
                                                const float* __restrict__ wf,
                                                float* __restrict__ s_src,
                                                float* __restrict__ s_trg, int NC) {
    int tid = blockIdx.x * 256 + threadIdx.x;
    if (tid >= NC) return;
    int cell = tid & 15;  // h*4 + r
    const uint4v* p  = (const uint4v*)(proj + (size_t)tid * 64);
    const float* av  = wf + WF_SSC + cell * 64;
    const float* bv  = wf + WF_STC + cell * 64;
    float accA = 0.f, accB = 0.f;
#pragma unroll
    for (int c = 0; c < 8; c++) {
        uint4v pv = p[c];
#pragma unroll
        for (int j = 0; j < 4; j++) {
            int k = c * 8 + j * 2;
            float p0 = bflo(pv[j]), p1 = bfhi(pv[j]);
            accA = fmaf(p0, av[k], accA);
            accA = fmaf(p1, av[k + 1], accA);
            accB = fmaf(p0, bv[k], accB);
            accB = fmaf(p1, bv[k + 1], accB);
        }
    }
    s_src[tid] = accA;
    s_trg[tid] = accB;
}

// ---------------------------------------------------------------------------
// CSR build: count -> hierarchical scan (3 kernels) -> fill
// ---------------------------------------------------------------------------
__global__ __launch_bounds__(256) void count_k(const int* __restrict__ trg,
                                               const int* __restrict__ rel,
                                               unsigned* __restrict__ counts, int E) {
    int e = blockIdx.x * 256 + threadIdx.x;
    if (e >= E) return;
    int g = clampi(trg[e], NNODES - 1);
    int r = clampi(rel[e], 3);
    atomicAdd(&counts[g * 4 + r], 1u);
}

// phase 1: block-local exclusive scan over 1024 bins; per-block total -> bsum
__global__ __launch_bounds__(256) void scan1_k(const unsigned* __restrict__ counts,
                                               unsigned* __restrict__ offsets,
                                               unsigned* __restrict__ bsum) {
    __shared__ unsigned ts[256];
    int t = threadIdx.x;
    int base = blockIdx.x * 1024 + t * 4;
    uint4v c = {0u, 0u, 0u, 0u};
    if (base + 3 < NBINS) c = *(const uint4v*)(counts + base);
    else {
#pragma unroll
        for (int j = 0; j < 4; j++) c[j] = (base + j < NBINS) ? counts[base + j] : 0u;
    }
    ts[t] = c[0] + c[1] + c[2] + c[3];
    __syncthreads();
    for (int off = 1; off < 256; off <<= 1) {
        unsigned v = (t >= off) ? ts[t - off] : 0u;
        __syncthreads();
        ts[t] += v;
        __syncthreads();
    }
    unsigned pre = (t == 0) ? 0u : ts[t - 1];
    uint4v o;
    o[0] = pre;
    o[1] = pre + c[0];
    o[2] = pre + c[0] + c[1];
    o[3] = pre + c[0] + c[1] + c[2];
    if (base + 3 < NBINS) *(uint4v*)(offsets + base) = o;
    else {
#pragma unroll
        for (int j = 0; j < 4; j++) if (base + j < NBINS) offsets[base + j] = o[j];
    }
    if (t == 255) bsum[blockIdx.x] = ts[255];
}

// phase 2: single small block scans the 196 block totals (exclusive)
__global__ __launch_bounds__(256) void scan2_k(unsigned* __restrict__ bsum,
                                               unsigned* __restrict__ offsets) {
    __shared__ unsigned ts[256];
    int t = threadIdx.x;
    unsigned v = (t < NSCANB) ? bsum[t] : 0u;
    ts[t] = v;
    __syncthreads();
    for (int off = 1; off < 256; off <<= 1) {
        unsigned u = (t >= off) ? ts[t - off] : 0u;
        __syncthreads();
        ts[t] += u;
        __syncthreads();
    }
    if (t < NSCANB) bsum[t] = (t == 0) ? 0u : ts[t - 1];
    if (t == 255) offsets[NBINS] = ts[255];
}

// phase 3: add block base, mirror into cursor
__global__ __launch_bounds__(256) void scan3_k(unsigned* __restrict__ offsets,
                                               unsigned* __restrict__ cursor,
                                               const unsigned* __restrict__ bsum) {
    int t = threadIdx.x;
    unsigned base = bsum[blockIdx.x];
    int idx = blockIdx.x * 1024 + t * 4;
    if (idx + 3 < NBINS) {
        uint4v o = *(const uint4v*)(offsets + idx);
        o[0] += base; o[1] += base; o[2] += base; o[3] += base;
        *(uint4v*)(offsets + idx) = o;
        *(uint4v*)(cursor + idx) = o;
    } else {
#pragma unroll
        for (int j = 0; j < 4; j++)
            if (idx + j < NBINS) {
                unsigned v = offsets[idx + j] + base;
                offsets[idx + j] = v;
                cursor[idx + j] = v;
            }
    }
}

__global__ __launch_bounds__(256) void fill_k(const int* __restrict__ src,
                                              const int* __restrict__ trg,
                                              const int* __restrict__ rel,
                                              const float* __restrict__ s_src,
                                              const float* __restrict__ s_trg,
                                              unsigned* __restrict__ cursor,
                                              unsigned* __restrict__ esrc,
                                              floatx4* __restrict__ eexp, int E) {
    int e = blockIdx.x * 256 + threadIdx.x;
    if (e >= E) return;
    int s = clampi(src[e], NNODES - 1);
    int g = clampi(trg[e], NNODES - 1);
    int r = clampi(rel[e], 3);
    unsigned pos = atomicAdd(&cursor[g * 4 + r], 1u);
    if (pos >= (unsigned)E) pos = E - 1;  // cannot happen; insurance
    esrc[pos] = (unsigned)s;
    floatx4 v;
#pragma unroll
    for (int h = 0; h < 4; h++) {
        float val = s_src[s * 16 + h * 4 + r] + s_trg[g * 16 + h * 4 + r];
        val = val > 0.f ? val : 0.2f * val;   // leaky_relu(0.2)
        v[h] = expf(val);
    }
    eexp[pos] = v;
}

// ---------------------------------------------------------------------------
// fused per-row (n,h,r): CSR gather-aggregate (normalized) -> agg row (bf16)
// + MLP (fp32 arena weights, vectorized) -> mish score
// ---------------------------------------------------------------------------
__global__ __launch_bounds__(256) void rowagg_mlp_k(const unsigned* __restrict__ offsets,
                                                    const unsigned* __restrict__ esrc,
                                                    const floatx4* __restrict__ eexp,
                                                    const unsigned short* __restrict__ proj,
                                                    const float* __restrict__ wf,
                                                    unsigned short* __restrict__ agg,
                                                    float* __restrict__ sc) {
    int row = blockIdx.x * 256 + threadIdx.x;  // row = n*16 + h*4 + r
    int n = row >> 4, h = (row >> 2) & 3, r = row & 3;
    int bin = n * 4 + r;
    unsigned beg = offsets[bin], end = offsets[bin + 1];

    float a[64];
#pragma unroll
    for (int k = 0; k < 64; k++) a[k] = 0.f;
    float den = 0.f;

    for (unsigned i = beg; i < end; i++) {
        int s = clampi((int)esrc[i], NNODES - 1);
        floatx4 pe = eexp[i];
        float p = pe[h];
        den += p;
        const uint4v* prow = (const uint4v*)(proj + ((size_t)(s * 4 + h) * 4 + r) * 64);
#pragma unroll
        for (int c = 0; c < 8; c++) {
            uint4v v = prow[c];
#pragma unroll
            for (int j = 0; j < 4; j++) {
                a[c * 8 + j * 2]     = fmaf(p, bflo(v[j]), a[c * 8 + j * 2]);
                a[c * 8 + j * 2 + 1] = fmaf(p, bfhi(v[j]), a[c * 8 + j * 2 + 1]);
            }
        }
    }
    float inv = 1.f / (den + 1e-16f);
#pragma unroll
    for (int k = 0; k < 64; k++) a[k] *= inv;

    // store agg row as bf16, layout (n, r, h, f)
    uint4v* arow = (uint4v*)(agg + ((size_t)(n * 4 + r) * 4 + h) * 64);
#pragma unroll
    for (int c = 0; c < 8; c++) {
        uint4v o;
#pragma unroll
        for (int j = 0; j < 4; j++)
            o[j] = f2bf(a[c * 8 + j * 2]) | (f2bf(a[c * 8 + j * 2 + 1]) << 16);
        arow[c] = o;
    }

    const float* W1f = wf + WF_W1;
    const float* b1f = wf + WF_B1;
    const float* W2f = wf + WF_W2;
    const float* b2f = wf + WF_B2;
    const float* W3f = wf + WF_W3;
    const float* b3f = wf + WF_B3;

    float b[64];
#pragma unroll
    for (int i = 0; i < 64; i++) {
        float acc = b1f[i];
        const floatx4* w = (const floatx4*)(W1f + i * 64);
#pragma unroll
        for (int c = 0; c < 16; c++) {
            floatx4 wv = w[c];
            acc = fmaf(wv[0], a[c * 4 + 0], acc);
            acc = fmaf(wv[1], a[c * 4 + 1], acc);
            acc = fmaf(wv[2], a[c * 4 + 2], acc);
            acc = fmaf(wv[3], a[c * 4 + 3], acc);
        }
        b[i] = fmaxf(acc, 0.f);
    }
#pragma unroll
    for (int i = 0; i < 64; i++) {
        float acc = b2f[i];
        const floatx4* w = (const floatx4*)(W2f + i * 64);
#pragma unroll
        for (int c = 0; c < 16; c++) {
            floatx4 wv = w[c];
            acc = fmaf(wv[0], b[c * 4 + 0], acc);
            acc = fmaf(wv[1], b[c * 4 + 1], acc);
            acc = fmaf(wv[2], b[c * 4 + 2], acc);
            acc = fmaf(wv[3], b[c * 4 + 3], acc);
        }
        a[i] = fmaxf(acc, 0.f);
    }
    float acc = b3f[0];
    const floatx4* w3 = (const floatx4*)W3f;
#pragma unroll
    for (int c = 0; c < 16; c++) {
        floatx4 wv = w3[c];
        acc = fmaf(wv[0], a[c * 4 + 0], acc);
        acc = fmaf(wv[1], a[c * 4 + 1], acc);
        acc = fmaf(wv[2], a[c * 4 + 2], acc);
        acc = fmaf(wv[3], a[c * 4 + 3], acc);
    }

    // stable softplus; mish = x * tanh(softplus(x))
    float sp = fmaxf(acc, 0.f) + log1pf(expf(-fabsf(acc)));
    sc[row] = acc * tanhf(sp);
}

// ---------------------------------------------------------------------------
// final: softmax over r, weighted sum, +skip(in d_out)+bias, ELU, LayerNorm
// ---------------------------------------------------------------------------
__global__ __launch_bounds__(256) void final_k(const unsigned short* __restrict__ agg,
                                               const float* __restrict__ sc,
                                               const float* __restrict__ wf,
                                               const unsigned* __restrict__ flag,
                                               unsigned short* __restrict__ out16,
                                               float* __restrict__ out32) {
    const bool f32 = (*flag != 0u);
    int n = blockIdx.x, t = threadIdx.x;
    int h = t >> 6, f = t & 63;
    float s0 = sc[n * 16 + h * 4 + 0];
    float s1 = sc[n * 16 + h * 4 + 1];
    float s2 = sc[n * 16 + h * 4 + 2];
    float s3 = sc[n * 16 + h * 4 + 3];
    float mx = fmaxf(fmaxf(s0, s1), fmaxf(s2, s3));
    float e0 = expf(s0 - mx), e1 = expf(s1 - mx), e2 = expf(s2 - mx), e3 = expf(s3 - mx);
    float inv = 1.f / (e0 + e1 + e2 + e3);
    size_t base = (size_t)n * 1024 + h * 64 + f;       // agg (n, r, h, f)
    float a0 = bf2f(agg[base]);
    float a1 = bf2f(agg[base + 256]);
    float a2 = bf2f(agg[base + 512]);
    float a3 = bf2f(agg[base + 768]);
    float v = (e0 * a0 + e1 * a1 + e2 * a2 + e3 * a3) * inv;
    size_t oidx = (size_t)n * 256 + t;
    float skipv = f32 ? out32[oidx] : bf2f(out16[oidx]);  // skip staged in d_out
    v += skipv + wf[WF_BIAS + t];
    v = v > 0.f ? v : expm1f(v);

    float s = v, q = v * v;
#pragma unroll
    for (int o = 1; o < 64; o <<= 1) {
        s += __shfl_xor(s, o);
        q += __shfl_xor(q, o);
    }
    __shared__ float red[8];
    __shared__ float stat[2];
    int wv = t >> 6, ln = t & 63;
    if (ln == 0) { red[wv] = s; red[4 + wv] = q; }
    __syncthreads();
    if (t == 0) {
        float S = red[0] + red[1] + red[2] + red[3];
        float Q = red[4] + red[5] + red[6] + red[7];
        float mu = S * (1.f / 256.f);
        float var = fmaxf(Q * (1.f / 256.f) - mu * mu, 0.f);
        stat[0] = mu;
        stat[1] = rsqrtf(var + 1e-5f);
    }
    __syncthreads();
    float o = (v - stat[0]) * stat[1] * wf[WF_GAMMA + t] + wf[WF_BETA + t];
    if (f32) out32[oidx] = o;
    else     out16[oidx] = (unsigned short)f2bf(o);
}

// ---------------------------------------------------------------------------
// workspace layout (bytes), total ~226.85 MB:
//   proj    bf16 (N,NH,NR,F)   0           .. 102,400,000
//   agg     bf16 (N,NR,NH,F)   102,400,000 .. 204,800,000
//   s_src   f32  (N,16)        204,800,000 .. 208,000,000
//   s_trg   f32  (N,16)        208,000,000 .. 211,200,000
//   eexp    f32x4 (E)          211,200,000 .. 219,200,000
//   esrc    u32  (E)           219,200,000 .. 221,200,000
//   counts  u32  (NBINS)       221,200,000 .. 222,000,000
//   offsets u32  (NBINS+1)     222,000,000 .. 222,800,016
//   cursor  u32  (NBINS)       222,800,016 .. 223,600,016
//   sc      f32  (N,16)        223,600,016 .. 226,800,016
//   wf      f32  (WF_TOT)      226,800,016 .. 226,844,820
//   flag    u32                226,844,824 .. 226,844,828
//   bsum    u32  (NSCANB)      226,844,832 .. 226,845,616
// ---------------------------------------------------------------------------
extern "C" void kernel_launch(void* const* d_in, const int* in_sizes, int n_in,
                              void* d_out, int out_size, void* d_ws, size_t ws_size,
                              hipStream_t stream) {
    if (ws_size < 226900000) return;  // clean diagnostic failure (absmax ~5.875)

    const void* x      = d_in[0];
    const int* src     = (const int*)d_in[1];
    const int* trg     = (const int*)d_in[2];
    const int* rel     = (const int*)d_in[3];
    const void* W_proj = d_in[5];
    const void* ssc    = d_in[6];
    const void* stc    = d_in[7];
    const void* W1     = d_in[8];
    const void* b1     = d_in[9];
    const void* W2     = d_in[10];
    const void* b2     = d_in[11];
    const void* W3     = d_in[12];
    const void* b3     = d_in[13];
    const void* W_skip = d_in[14];
    const void* bias   = d_in[15];
    const void* gamma  = d_in[16];
    const void* beta   = d_in[17];
    unsigned short* out16 = (unsigned short*)d_out;
    float* out32          = (float*)d_out;

    char* w = (char*)d_ws;
    unsigned short* proj = (unsigned short*)(w + 0);
    unsigned short* agg  = (unsigned short*)(w + 102400000);
    float* s_src         = (float*)(w + 204800000);
    float* s_trg         = (float*)(w + 208000000);
    floatx4* eexp        = (floatx4*)(w + 211200000);
    unsigned* esrc       = (unsigned*)(w + 219200000);
    unsigned* counts     = (unsigned*)(w + 221200000);
    unsigned* offsets    = (unsigned*)(w + 222000000);
    unsigned* cursor     = (unsigned*)(w + 222800016);
    float* sc            = (float*)(w + 223600016);
    float* wf            = (float*)(w + 226800016);
    unsigned* flag       = (unsigned*)(w + 226844824);
    unsigned* bsum       = (unsigned*)(w + 226844832);

    hipMemsetAsync(counts, 0, NBINS * 4, stream);

    probe_k<<<1, 256, 0, stream>>>((const unsigned short*)x, flag);
    wconv_k<<<1, 1024, 0, stream>>>(W1, b1, W2, b2, W3, b3, ssc, stc, bias, gamma, beta,
                                    flag, wf);
    // proj = x @ W_proj^T (internal bf16)
    gemm_bt<<<dim3(196, 16), 256, 0, stream>>>(x, W_proj, proj, nullptr,
                                               NNODES, 1024, 256, flag, 0);
    // skip = x @ W_skip^T -> d_out (dtype per flag)
    gemm_bt<<<dim3(196, 4), 256, 0, stream>>>(x, W_skip, out16, out32,
                                              NNODES, 256, 256, flag, 1);
    scores_k<<<3125, 256, 0, stream>>>(proj, wf, s_src, s_trg, NNODES * 16);
    count_k<<<1954, 256, 0, stream>>>(trg, rel, counts, NEDGES);
    scan1_k<<<NSCANB, 256, 0, stream>>>(counts, offsets, bsum);
    scan2_k<<<1, 256, 0, stream>>>(bsum, offsets);
    scan3_k<<<NSCANB, 256, 0, stream>>>(offsets, cursor, bsum);
    fill_k<<<1954, 256, 0, stream>>>(src, trg, rel, s_src, s_trg, cursor, esrc, eexp, NEDGES);
    rowagg_mlp_k<<<3125, 256, 0, stream>>>(offsets, esrc, eexp, proj, wf, agg, sc);
    final_k<<<NNODES, 256, 0, stream>>>(agg, sc, wf, flag, out16, out32);
}

// Round 6
// 798.873 us; speedup vs baseline: 1.8847x; 1.2673x over previous
//
#include <hip/hip_runtime.h>

#define NNODES 50000
#define NEDGES 500000
#define NBINS  (NNODES * 4)
#define NSCANB 196   // ceil(NBINS / 1024)

// wf fp32 arena offsets (in floats)
#define WF_W1    0
#define WF_B1    4096
#define WF_W2    4160
#define WF_B2    8256
#define WF_W3    8320
#define WF_B3    8384
#define WF_SSC   8385
#define WF_STC   9409
#define WF_BIAS  10433
#define WF_GAMMA 10689
#define WF_BETA  10945
#define WF_TOT   11201

typedef __attribute__((ext_vector_type(8))) short short8;
typedef __attribute__((ext_vector_type(4))) float floatx4;
typedef __attribute__((ext_vector_type(4))) unsigned int uint4v;

__device__ __forceinline__ float bf2f(unsigned short u) {
    return __uint_as_float(((unsigned)u) << 16);
}
__device__ __forceinline__ unsigned f2bf(float f) {
    unsigned u = __float_as_uint(f);
    u += 0x7fffu + ((u >> 16) & 1u);
    return u >> 16;
}
__device__ __forceinline__ float bflo(unsigned u) { return __uint_as_float(u << 16); }
__device__ __forceinline__ float bfhi(unsigned u) { return __uint_as_float(u & 0xffff0000u); }
__device__ __forceinline__ int clampi(int v, int hi) { return v < 0 ? 0 : (v > hi ? hi : v); }

__device__ __forceinline__ short8 pack_bf16(const float* p) {
    short8 r;
#pragma unroll
    for (int j = 0; j < 8; j++) r[j] = (short)f2bf(p[j]);
    return r;
}

// ---------------------------------------------------------------------------
// dtype probe: flag=1 means inputs are fp32 (mantissa halves decode huge)
// ---------------------------------------------------------------------------
__global__ __launch_bounds__(256) void probe_k(const unsigned short* __restrict__ xs,
                                               unsigned* __restrict__ flag) {
    __shared__ unsigned cnt;
    if (threadIdx.x == 0) cnt = 0;
    __syncthreads();
    unsigned local = 0;
    for (int i = threadIdx.x; i < 8192; i += 256) {
        float v = bf2f(xs[i]);
        if (!(fabsf(v) < 1e10f)) local++;
    }
    atomicAdd(&cnt, local);
    __syncthreads();
    if (threadIdx.x == 0) *flag = (cnt > 256u) ? 1u : 0u;
}

// ---------------------------------------------------------------------------
// polymorphic small-param conversion into fp32 arena
// ---------------------------------------------------------------------------
__device__ __forceinline__ float ldf(const void* p, int i, bool f32) {
    return f32 ? ((const float*)p)[i] : bf2f(((const unsigned short*)p)[i]);
}

__global__ __launch_bounds__(1024) void wconv_k(const void* W1, const void* b1,
                                                const void* W2, const void* b2,
                                                const void* W3, const void* b3,
                                                const void* ssc, const void* stc,
                                                const void* bias, const void* gamma,
                                                const void* beta,
                                                const unsigned* __restrict__ flag,
                                                float* __restrict__ wf) {
    bool f32 = (*flag != 0u);
    for (int i = threadIdx.x; i < WF_TOT; i += 1024) {
        float v;
        if (i < WF_B1)          v = ldf(W1, i - WF_W1, f32);
        else if (i < WF_W2)     v = ldf(b1, i - WF_B1, f32);
        else if (i < WF_B2)     v = ldf(W2, i - WF_W2, f32);
        else if (i < WF_W3)     v = ldf(b2, i - WF_B2, f32);
        else if (i < WF_B3)     v = ldf(W3, i - WF_W3, f32);
        else if (i < WF_SSC)    v = ldf(b3, i - WF_B3, f32);
        else if (i < WF_STC)    v = ldf(ssc, i - WF_SSC, f32);
        else if (i < WF_BIAS)   v = ldf(stc, i - WF_STC, f32);
        else if (i < WF_GAMMA)  v = ldf(bias, i - WF_BIAS, f32);
        else if (i < WF_BETA)   v = ldf(gamma, i - WF_GAMMA, f32);
        else                    v = ldf(beta, i - WF_BETA, f32);
        wf[i] = v;
    }
}

// ---------------------------------------------------------------------------
// polymorphic MFMA fragment load
// ---------------------------------------------------------------------------
__device__ __forceinline__ short8 ldfrag(const void* P, size_t idx, bool f32) {
    if (f32) {
        const float* pf = (const float*)P;
        floatx4 a = *(const floatx4*)(pf + idx);
        floatx4 b = *(const floatx4*)(pf + idx + 4);
        short8 r;
        r[0] = (short)f2bf(a[0]); r[1] = (short)f2bf(a[1]);
        r[2] = (short)f2bf(a[2]); r[3] = (short)f2bf(a[3]);
        r[4] = (short)f2bf(b[0]); r[5] = (short)f2bf(b[1]);
        r[6] = (short)f2bf(b[2]); r[7] = (short)f2bf(b[3]);
        return r;
    }
    return *(const short8*)((const unsigned short*)P + idx);
}

// ---------------------------------------------------------------------------
// GEMM: C[m, j] = sum_k A[m,k] * B[j,k]
// ---------------------------------------------------------------------------
__global__ __launch_bounds__(256) void gemm_bt(const void* __restrict__ A,
                                               const void* __restrict__ B,
                                               unsigned short* __restrict__ C16,
                                               float* __restrict__ C32,
                                               int M, int Nout, int K,
                                               const unsigned* __restrict__ flag,
                                               int c_poly) {
    const bool f32 = (*flag != 0u);
    const bool cf32 = f32 && (c_poly != 0);
    const int wave = threadIdx.x >> 6;
    const int lane = threadIdx.x & 63;
    const int l15  = lane & 15;
    const int q    = lane >> 4;
    const int m0   = blockIdx.x * 256 + wave * 64;
    const int n0   = blockIdx.y * 64;

    floatx4 acc[4][4];
#pragma unroll
    for (int i = 0; i < 4; i++)
#pragma unroll
        for (int j = 0; j < 4; j++) acc[i][j] = (floatx4){0.f, 0.f, 0.f, 0.f};

    for (int kc = 0; kc < K; kc += 32) {
        short8 af[4], bfr[4];
#pragma unroll
        for (int mt = 0; mt < 4; mt++) {
            int row = m0 + mt * 16 + l15;
            row = row < M ? row : M - 1;
            af[mt] = ldfrag(A, (size_t)row * K + kc + q * 8, f32);
        }
#pragma unroll
        for (int nt = 0; nt < 4; nt++) {
            int col = n0 + nt * 16 + l15;
            bfr[nt] = ldfrag(B, (size_t)col * K + kc + q * 8, f32);
        }
#pragma unroll
        for (int mt = 0; mt < 4; mt++)
#pragma unroll
            for (int nt = 0; nt < 4; nt++)
                acc[mt][nt] = __builtin_amdgcn_mfma_f32_16x16x32_bf16(af[mt], bfr[nt],
                                                                     acc[mt][nt], 0, 0, 0);
    }

#pragma unroll
    for (int mt = 0; mt < 4; mt++)
#pragma unroll
        for (int nt = 0; nt < 4; nt++)
#pragma unroll
            for (int r = 0; r < 4; r++) {
                int row = m0 + mt * 16 + q * 4 + r;
                int col = n0 + nt * 16 + l15;
                if (row < M) {
                    size_t idx = (size_t)row * Nout + col;
                    float v = acc[mt][nt][r];
                    if (cf32) C32[idx] = v;
                    else      C16[idx] = (unsigned short)f2bf(v);
                }
            }
}

// ---------------------------------------------------------------------------
// per (n,h,r): s_src / s_trg dots
// ---------------------------------------------------------------------------
__global__ __launch_bounds__(256) void scores_k(const unsigned short* __restrict__ proj,
                                                const float* __restrict__ wf,
                                                float* __restrict__ s_src,
                                                float* __restrict__ s_trg, int NC) {
    int tid = blockIdx.x * 256 + threadIdx.x;
    if (tid >= NC) return;
    int cell = tid & 15;
    const uint4v* p  = (const uint4v*)(proj + (size_t)tid * 64);
    const float* av  = wf + WF_SSC + cell * 64;
    const float* bv  = wf + WF_STC + cell * 64;
    float accA = 0.f, accB = 0.f;
#pragma unroll
    for (int c = 0; c < 8; c++) {
        uint4v pv = p[c];
#pragma unroll
        for (int j = 0; j < 4; j++) {
            int k = c * 8 + j * 2;
            float p0 = bflo(pv[j]), p1 = bfhi(pv[j]);
            accA = fmaf(p0, av[k], accA);
            accA = fmaf(p1, av[k + 1], accA);
            accB = fmaf(p0, bv[k], accB);
            accB = fmaf(p1, bv[k + 1], accB);
        }
    }
    s_src[tid] = accA;
    s_trg[tid] = accB;
}

// ---------------------------------------------------------------------------
// CSR build: count -> hierarchical scan -> fill
// ---------------------------------------------------------------------------
__global__ __launch_bounds__(256) void count_k(const int* __restrict__ trg,
                                               const int* __restrict__ rel,
                                               unsigned* __restrict__ counts, int E) {
    int e = blockIdx.x * 256 + threadIdx.x;
    if (e >= E) return;
    int g = clampi(trg[e], NNODES - 1);
    int r = clampi(rel[e], 3);
    atomicAdd(&counts[g * 4 + r], 1u);
}

__global__ __launch_bounds__(256) void scan1_k(const unsigned* __restrict__ counts,
                                               unsigned* __restrict__ offsets,
                                               unsigned* __restrict__ bsum) {
    __shared__ unsigned ts[256];
    int t = threadIdx.x;
    int base = blockIdx.x * 1024 + t * 4;
    uint4v c = {0u, 0u, 0u, 0u};
    if (base + 3 < NBINS) c = *(const uint4v*)(counts + base);
    else {
#pragma unroll
        for (int j = 0; j < 4; j++) c[j] = (base + j < NBINS) ? counts[base + j] : 0u;
    }
    ts[t] = c[0] + c[1] + c[2] + c[3];
    __syncthreads();
    for (int off = 1; off < 256; off <<= 1) {
        unsigned v = (t >= off) ? ts[t - off] : 0u;
        __syncthreads();
        ts[t] += v;
        __syncthreads();
    }
    unsigned pre = (t == 0) ? 0u : ts[t - 1];
    uint4v o;
    o[0] = pre;
    o[1] = pre + c[0];
    o[2] = pre + c[0] + c[1];
    o[3] = pre + c[0] + c[1] + c[2];
    if (base + 3 < NBINS) *(uint4v*)(offsets + base) = o;
    else {
#pragma unroll
        for (int j = 0; j < 4; j++) if (base + j < NBINS) offsets[base + j] = o[j];
    }
    if (t == 255) bsum[blockIdx.x] = ts[255];
}

__global__ __launch_bounds__(256) void scan2_k(unsigned* __restrict__ bsum,
                                               unsigned* __restrict__ offsets) {
    __shared__ unsigned ts[256];
    int t = threadIdx.x;
    unsigned v = (t < NSCANB) ? bsum[t] : 0u;
    ts[t] = v;
    __syncthreads();
    for (int off = 1; off < 256; off <<= 1) {
        unsigned u = (t >= off) ? ts[t - off] : 0u;
        __syncthreads();
        ts[t] += u;
        __syncthreads();
    }
    if (t < NSCANB) bsum[t] = (t == 0) ? 0u : ts[t - 1];
    if (t == 255) offsets[NBINS] = ts[255];
}

__global__ __launch_bounds__(256) void scan3_k(unsigned* __restrict__ offsets,
                                               unsigned* __restrict__ cursor,
                                               const unsigned* __restrict__ bsum) {
    int t = threadIdx.x;
    unsigned base = bsum[blockIdx.x];
    int idx = blockIdx.x * 1024 + t * 4;
    if (idx + 3 < NBINS) {
        uint4v o = *(const uint4v*)(offsets + idx);
        o[0] += base; o[1] += base; o[2] += base; o[3] += base;
        *(uint4v*)(offsets + idx) = o;
        *(uint4v*)(cursor + idx) = o;
    } else {
#pragma unroll
        for (int j = 0; j < 4; j++)
            if (idx + j < NBINS) {
                unsigned v = offsets[idx + j] + base;
                offsets[idx + j] = v;
                cursor[idx + j] = v;
            }
    }
}

__global__ __launch_bounds__(256) void fill_k(const int* __restrict__ src,
                                              const int* __restrict__ trg,
                                              const int* __restrict__ rel,
                                              const float* __restrict__ s_src,
                                              const float* __restrict__ s_trg,
                                              unsigned* __restrict__ cursor,
                                              unsigned* __restrict__ esrc,
                                              floatx4* __restrict__ eexp, int E) {
    int e = blockIdx.x * 256 + threadIdx.x;
    if (e >= E) return;
    int s = clampi(src[e], NNODES - 1);
    int g = clampi(trg[e], NNODES - 1);
    int r = clampi(rel[e], 3);
    unsigned pos = atomicAdd(&cursor[g * 4 + r], 1u);
    if (pos >= (unsigned)E) pos = E - 1;
    esrc[pos] = (unsigned)s;
    floatx4 v;
#pragma unroll
    for (int h = 0; h < 4; h++) {
        float val = s_src[s * 16 + h * 4 + r] + s_trg[g * 16 + h * 4 + r];
        val = val > 0.f ? val : 0.2f * val;
        v[h] = expf(val);
    }
    eexp[pos] = v;
}

// ---------------------------------------------------------------------------
// aggregation: one WAVE per bin (n,r); lanes = f. Coalesced 128B proj loads.
// agg storage layout (n, r, h, f) bf16.
// ---------------------------------------------------------------------------
__global__ __launch_bounds__(256) void rowagg2_k(const unsigned* __restrict__ offsets,
                                                 const unsigned* __restrict__ esrc,
                                                 const floatx4* __restrict__ eexp,
                                                 const unsigned short* __restrict__ proj,
                                                 unsigned short* __restrict__ agg) {
    int wave = threadIdx.x >> 6, f = threadIdx.x & 63;
    int bin = blockIdx.x * 4 + wave;
    if (bin >= NBINS) return;
    int r = bin & 3;
    unsigned beg = offsets[bin], end = offsets[bin + 1];

    float a0 = 0.f, a1 = 0.f, a2 = 0.f, a3 = 0.f;
    float d0 = 0.f, d1 = 0.f, d2 = 0.f, d3 = 0.f;
    for (unsigned i = beg; i < end; i++) {
        unsigned s = esrc[i];                        // clamped at fill
        floatx4 pe = eexp[i];                        // broadcast
        const unsigned short* pb = proj + (size_t)s * 1024 + r * 64 + f;
        float v0 = bf2f(pb[0]);
        float v1 = bf2f(pb[256]);
        float v2 = bf2f(pb[512]);
        float v3 = bf2f(pb[768]);
        a0 = fmaf(pe[0], v0, a0); d0 += pe[0];
        a1 = fmaf(pe[1], v1, a1); d1 += pe[1];
        a2 = fmaf(pe[2], v2, a2); d2 += pe[2];
        a3 = fmaf(pe[3], v3, a3); d3 += pe[3];
    }
    size_t ob = (size_t)bin * 256 + f;               // (bin, h, f)
    agg[ob]       = (unsigned short)f2bf(a0 / (d0 + 1e-16f));
    agg[ob + 64]  = (unsigned short)f2bf(a1 / (d1 + 1e-16f));
    agg[ob + 128] = (unsigned short)f2bf(a2 / (d2 + 1e-16f));
    agg[ob + 192] = (unsigned short)f2bf(a3 / (d3 + 1e-16f));
}

// ---------------------------------------------------------------------------
// MFMA MLP: per wave, 4 tiles of 16 rows: relu(W1.a+b1) -> relu(W2.h+b2)
// -> mish(W3.h+b3). Weights in reg-resident bf16 fragments; C->A transpose
// via padded LDS (stride 68).
// ---------------------------------------------------------------------------
__global__ __launch_bounds__(256, 2) void mlp_mfma_k(const unsigned short* __restrict__ agg,
                                                     const float* __restrict__ wf,
                                                     float* __restrict__ sc) {
    __shared__ float lds[4][16 * 68];
    const int wave = threadIdx.x >> 6;
    const int lane = threadIdx.x & 63;
    const int l15 = lane & 15, q = lane >> 4;
    float* L = lds[wave];

    short8 w1f[2][4], w2f[2][4];
#pragma unroll
    for (int ks = 0; ks < 2; ks++)
#pragma unroll
        for (int nt = 0; nt < 4; nt++) {
            w1f[ks][nt] = pack_bf16(wf + WF_W1 + (nt * 16 + l15) * 64 + ks * 32 + q * 8);
            w2f[ks][nt] = pack_bf16(wf + WF_W2 + (nt * 16 + l15) * 64 + ks * 32 + q * 8);
        }
    float b1v[4], b2v[4], w3v[4];
#pragma unroll
    for (int nt = 0; nt < 4; nt++) {
        b1v[nt] = wf[WF_B1 + nt * 16 + l15];
        b2v[nt] = wf[WF_B2 + nt * 16 + l15];
        w3v[nt] = wf[WF_W3 + nt * 16 + l15];
    }
    float b3v = wf[WF_B3];

    int wave_id = blockIdx.x * 4 + wave;
#pragma unroll 1
    for (int t = 0; t < 4; t++) {
        int row0 = (wave_id * 4 + t) * 16;
        // layer 1: A from agg (bf16 global, coalesced)
        short8 a1[2];
#pragma unroll
        for (int ks = 0; ks < 2; ks++)
            a1[ks] = *(const short8*)(agg + (size_t)(row0 + l15) * 64 + ks * 32 + q * 8);
        floatx4 acc1[4];
#pragma unroll
        for (int nt = 0; nt < 4; nt++) {
            acc1[nt] = (floatx4){0.f, 0.f, 0.f, 0.f};
            acc1[nt] = __builtin_amdgcn_mfma_f32_16x16x32_bf16(a1[0], w1f[0][nt], acc1[nt], 0, 0, 0);
            acc1[nt] = __builtin_amdgcn_mfma_f32_16x16x32_bf16(a1[1], w1f[1][nt], acc1[nt], 0, 0, 0);
        }
        __syncthreads();   // prev iteration's LDS reads complete
#pragma unroll
        for (int nt = 0; nt < 4; nt++)
#pragma unroll
            for (int rg = 0; rg < 4; rg++)
                L[(q * 4 + rg) * 68 + nt * 16 + l15] = fmaxf(acc1[nt][rg] + b1v[nt], 0.f);
        __syncthreads();
        // layer 2: A from LDS transpose
        short8 a2[2];
#pragma unroll
        for (int ks = 0; ks < 2; ks++) {
            short8 rr;
#pragma unroll
            for (int j = 0; j < 8; j++)
                rr[j] = (short)f2bf(L[l15 * 68 + ks * 32 + q * 8 + j]);
            a2[ks] = rr;
        }
        floatx4 acc2[4];
#pragma unroll
        for (int nt = 0; nt < 4; nt++) {
            acc2[nt] = (floatx4){0.f, 0.f, 0.f, 0.f};
            acc2[nt] = __builtin_amdgcn_mfma_f32_16x16x32_bf16(a2[0], w2f[0][nt], acc2[nt], 0, 0, 0);
            acc2[nt] = __builtin_amdgcn_mfma_f32_16x16x32_bf16(a2[1], w2f[1][nt], acc2[nt], 0, 0, 0);
        }
        // layer 3: dot with w3 in C layout + 16-lane reduce
        float p[4];
#pragma unroll
        for (int rg = 0; rg < 4; rg++) {
            float s = 0.f;
#pragma unroll
            for (int nt = 0; nt < 4; nt++)
                s = fmaf(fmaxf(acc2[nt][rg] + b2v[nt], 0.f), w3v[nt], s);
            p[rg] = s;
        }
#pragma unroll
        for (int off = 1; off < 16; off <<= 1) {
#pragma unroll
            for (int rg = 0; rg < 4; rg++) p[rg] += __shfl_xor(p[rg], off);
        }
        if (l15 == 0) {
#pragma unroll
            for (int rg = 0; rg < 4; rg++) {
                float acc = p[rg] + b3v;
                float sp = fmaxf(acc, 0.f) + log1pf(expf(-fabsf(acc)));
                float m = acc * tanhf(sp);
                int s_id = row0 + q * 4 + rg;          // storage order (n, r, h)
                int n = s_id >> 4, r = (s_id >> 2) & 3, h = s_id & 3;
                sc[n * 16 + h * 4 + r] = m;
            }
        }
    }
}

// ---------------------------------------------------------------------------
// final: softmax over r, weighted sum, +skip(in d_out)+bias, ELU, LayerNorm
// ---------------------------------------------------------------------------
__global__ __launch_bounds__(256) void final_k(const unsigned short* __restrict__ agg,
                                               const float* __restrict__ sc,
                                               const float* __restrict__ wf,
                                               const unsigned* __restrict__ flag,
                                               unsigned short* __restrict__ out16,
                                               float* __restrict__ out32) {
    const bool f32 = (*flag != 0u);
    int n = blockIdx.x, t = threadIdx.x;
    int h = t >> 6, f = t & 63;
    float s0 = sc[n * 16 + h * 4 + 0];
    float s1 = sc[n * 16 + h * 4 + 1];
    float s2 = sc[n * 16 + h * 4 + 2];
    float s3 = sc[n * 16 + h * 4 + 3];
    float mx = fmaxf(fmaxf(s0, s1), fmaxf(s2, s3));
    float e0 = expf(s0 - mx), e1 = expf(s1 - mx), e2 = expf(s2 - mx), e3 = expf(s3 - mx);
    float inv = 1.f / (e0 + e1 + e2 + e3);
    size_t base = (size_t)n * 1024 + h * 64 + f;
    float a0 = bf2f(agg[base]);
    float a1 = bf2f(agg[base + 256]);
    float a2 = bf2f(agg[base + 512]);
    float a3 = bf2f(agg[base + 768]);
    float v = (e0 * a0 + e1 * a1 + e2 * a2 + e3 * a3) * inv;
    size_t oidx = (size_t)n * 256 + t;
    float skipv = f32 ? out32[oidx] : bf2f(out16[oidx]);
    v += skipv + wf[WF_BIAS + t];
    v = v > 0.f ? v : expm1f(v);

    float s = v, qq = v * v;
#pragma unroll
    for (int o = 1; o < 64; o <<= 1) {
        s += __shfl_xor(s, o);
        qq += __shfl_xor(qq, o);
    }
    __shared__ float red[8];
    __shared__ float stat[2];
    int wv = t >> 6, ln = t & 63;
    if (ln == 0) { red[wv] = s; red[4 + wv] = qq; }
    __syncthreads();
    if (t == 0) {
        float S = red[0] + red[1] + red[2] + red[3];
        float Q = red[4] + red[5] + red[6] + red[7];
        float mu = S * (1.f / 256.f);
        float var = fmaxf(Q * (1.f / 256.f) - mu * mu, 0.f);
        stat[0] = mu;
        stat[1] = rsqrtf(var + 1e-5f);
    }
    __syncthreads();
    float o = (v - stat[0]) * stat[1] * wf[WF_GAMMA + t] + wf[WF_BETA + t];
    if (f32) out32[oidx] = o;
    else     out16[oidx] = (unsigned short)f2bf(o);
}

// ---------------------------------------------------------------------------
// workspace layout unchanged (~226.85 MB)
// ---------------------------------------------------------------------------
extern "C" void kernel_launch(void* const* d_in, const int* in_sizes, int n_in,
                              void* d_out, int out_size, void* d_ws, size_t ws_size,
                              hipStream_t stream) {
    if (ws_size < 226900000) return;

    const void* x      = d_in[0];
    const int* src     = (const int*)d_in[1];
    const int* trg     = (const int*)d_in[2];
    const int* rel     = (const int*)d_in[3];
    const void* W_proj = d_in[5];
    const void* ssc    = d_in[6];
    const void* stc    = d_in[7];
    const void* W1     = d_in[8];
    const void* b1     = d_in[9];
    const void* W2     = d_in[10];
    const void* b2     = d_in[11];
    const void* W3     = d_in[12];
    const void* b3     = d_in[13];
    const void* W_skip = d_in[14];
    const void* bias   = d_in[15];
    const void* gamma  = d_in[16];
    const void* beta   = d_in[17];
    unsigned short* out16 = (unsigned short*)d_out;
    float* out32          = (float*)d_out;

    char* w = (char*)d_ws;
    unsigned short* proj = (unsigned short*)(w + 0);
    unsigned short* agg  = (unsigned short*)(w + 102400000);
    float* s_src         = (float*)(w + 204800000);
    float* s_trg         = (float*)(w + 208000000);
    floatx4* eexp        = (floatx4*)(w + 211200000);
    unsigned* esrc       = (unsigned*)(w + 219200000);
    unsigned* counts     = (unsigned*)(w + 221200000);
    unsigned* offsets    = (unsigned*)(w + 222000000);
    unsigned* cursor     = (unsigned*)(w + 222800016);
    float* sc            = (float*)(w + 223600016);
    float* wf            = (float*)(w + 226800016);
    unsigned* flag       = (unsigned*)(w + 226844824);
    unsigned* bsum       = (unsigned*)(w + 226844832);

    hipMemsetAsync(counts, 0, NBINS * 4, stream);

    probe_k<<<1, 256, 0, stream>>>((const unsigned short*)x, flag);
    wconv_k<<<1, 1024, 0, stream>>>(W1, b1, W2, b2, W3, b3, ssc, stc, bias, gamma, beta,
                                    flag, wf);
    gemm_bt<<<dim3(196, 16), 256, 0, stream>>>(x, W_proj, proj, nullptr,
                                               NNODES, 1024, 256, flag, 0);
    gemm_bt<<<dim3(196, 4), 256, 0, stream>>>(x, W_skip, out16, out32,
                                              NNODES, 256, 256, flag, 1);
    scores_k<<<3125, 256, 0, stream>>>(proj, wf, s_src, s_trg, NNODES * 16);
    count_k<<<1954, 256, 0, stream>>>(trg, rel, counts, NEDGES);
    scan1_k<<<NSCANB, 256, 0, stream>>>(counts, offsets, bsum);
    scan2_k<<<1, 256, 0, stream>>>(bsum, offsets);
    scan3_k<<<NSCANB, 256, 0, stream>>>(offsets, cursor, bsum);
    fill_k<<<1954, 256, 0, stream>>>(src, trg, rel, s_src, s_trg, cursor, esrc, eexp, NEDGES);
    rowagg2_k<<<NBINS / 4, 256, 0, stream>>>(offsets, esrc, eexp, proj, agg);
    mlp_mfma_k<<<3125, 256, 0, stream>>>(agg, wf, sc);
    final_k<<<NNODES, 256, 0, stream>>>(agg, sc, wf, flag, out16, out32);
}

// Round 7
// 659.832 us; speedup vs baseline: 2.2818x; 1.2107x over previous
//
#include <hip/hip_runtime.h>

#define NNODES 50000
#define NEDGES 500000
#define NBINS  (NNODES * 4)
#define NSCANB 196   // ceil(NBINS / 1024)
#define MPAD   50176 // 196*256

// wf fp32 arena offsets (in floats)
#define WF_W1    0
#define WF_B1    4096
#define WF_W2    4160
#define WF_B2    8256
#define WF_W3    8320
#define WF_B3    8384
#define WF_SSC   8385
#define WF_STC   9409
#define WF_BIAS  10433
#define WF_GAMMA 10689
#define WF_BETA  10945
#define WF_TOT   11201

typedef __attribute__((ext_vector_type(8))) short short8;
typedef __attribute__((ext_vector_type(4))) short short4v;
typedef __attribute__((ext_vector_type(4))) float floatx4;
typedef __attribute__((ext_vector_type(4))) unsigned int uint4v;

__device__ __forceinline__ float bf2f(unsigned short u) {
    return __uint_as_float(((unsigned)u) << 16);
}
__device__ __forceinline__ unsigned f2bf(float f) {
    unsigned u = __float_as_uint(f);
    u += 0x7fffu + ((u >> 16) & 1u);
    return u >> 16;
}
__device__ __forceinline__ float bflo(unsigned u) { return __uint_as_float(u << 16); }
__device__ __forceinline__ float bfhi(unsigned u) { return __uint_as_float(u & 0xffff0000u); }
__device__ __forceinline__ int clampi(int v, int hi) { return v < 0 ? 0 : (v > hi ? hi : v); }

__device__ __forceinline__ short8 pack_bf16(const float* p) {
    short8 r;
#pragma unroll
    for (int j = 0; j < 8; j++) r[j] = (short)f2bf(p[j]);
    return r;
}

// ---------------------------------------------------------------------------
// dtype probe: flag=1 means inputs are fp32
// ---------------------------------------------------------------------------
__global__ __launch_bounds__(256) void probe_k(const unsigned short* __restrict__ xs,
                                               unsigned* __restrict__ flag) {
    __shared__ unsigned cnt;
    if (threadIdx.x == 0) cnt = 0;
    __syncthreads();
    unsigned local = 0;
    for (int i = threadIdx.x; i < 8192; i += 256) {
        float v = bf2f(xs[i]);
        if (!(fabsf(v) < 1e10f)) local++;
    }
    atomicAdd(&cnt, local);
    __syncthreads();
    if (threadIdx.x == 0) *flag = (cnt > 256u) ? 1u : 0u;
}

// ---------------------------------------------------------------------------
// polymorphic small-param conversion into fp32 arena
// ---------------------------------------------------------------------------
__device__ __forceinline__ float ldf(const void* p, int i, bool f32) {
    return f32 ? ((const float*)p)[i] : bf2f(((const unsigned short*)p)[i]);
}

__global__ __launch_bounds__(1024) void wconv_k(const void* W1, const void* b1,
                                                const void* W2, const void* b2,
                                                const void* W3, const void* b3,
                                                const void* ssc, const void* stc,
                                                const void* bias, const void* gamma,
                                                const void* beta,
                                                const unsigned* __restrict__ flag,
                                                float* __restrict__ wf) {
    bool f32 = (*flag != 0u);
    for (int i = threadIdx.x; i < WF_TOT; i += 1024) {
        float v;
        if (i < WF_B1)          v = ldf(W1, i - WF_W1, f32);
        else if (i < WF_W2)     v = ldf(b1, i - WF_B1, f32);
        else if (i < WF_B2)     v = ldf(W2, i - WF_W2, f32);
        else if (i < WF_W3)     v = ldf(b2, i - WF_B2, f32);
        else if (i < WF_B3)     v = ldf(W3, i - WF_W3, f32);
        else if (i < WF_SSC)    v = ldf(b3, i - WF_B3, f32);
        else if (i < WF_STC)    v = ldf(ssc, i - WF_SSC, f32);
        else if (i < WF_BIAS)   v = ldf(stc, i - WF_STC, f32);
        else if (i < WF_GAMMA)  v = ldf(bias, i - WF_BIAS, f32);
        else if (i < WF_BETA)   v = ldf(gamma, i - WF_GAMMA, f32);
        else                    v = ldf(beta, i - WF_BETA, f32);
        wf[i] = v;
    }
}

// ---------------------------------------------------------------------------
// bulk matrix conversion (fp32|bf16 -> bf16), zero-padded to npad elems
// ---------------------------------------------------------------------------
__global__ __launch_bounds__(256) void convbf_k(const void* __restrict__ src,
                                                unsigned short* __restrict__ dst,
                                                int nelem, int npad,
                                                const unsigned* __restrict__ flag) {
    int i8 = (blockIdx.x * 256 + threadIdx.x) * 8;
    if (i8 >= npad) return;
    short8 o;
    if (i8 < nelem) {
        if (*flag) {
            const float* pf = (const float*)src + i8;
            floatx4 a = *(const floatx4*)pf;
            floatx4 b = *(const floatx4*)(pf + 4);
            o[0] = (short)f2bf(a[0]); o[1] = (short)f2bf(a[1]);
            o[2] = (short)f2bf(a[2]); o[3] = (short)f2bf(a[3]);
            o[4] = (short)f2bf(b[0]); o[5] = (short)f2bf(b[1]);
            o[6] = (short)f2bf(b[2]); o[7] = (short)f2bf(b[3]);
        } else {
            o = *(const short8*)((const unsigned short*)src + i8);
        }
    } else {
#pragma unroll
        for (int j = 0; j < 8; j++) o[j] = 0;
    }
    *(short8*)(dst + i8) = o;
}

// ---------------------------------------------------------------------------
// bf16 GEMM: C[m, j] = sum_k A[m,k] * B[j,k]; A padded so no row clamp.
// permute=1: proj column remap (h,r,f)->(r,h,f) (uniform per block-column).
// c_poly=1: C dtype per flag (d_out), else bf16.
// ---------------------------------------------------------------------------
__global__ __launch_bounds__(256) void gemm_bt2(const unsigned short* __restrict__ A,
                                                const unsigned short* __restrict__ B,
                                                unsigned short* __restrict__ C16,
                                                float* __restrict__ C32,
                                                int M, int Nout, int K,
                                                const unsigned* __restrict__ flag,
                                                int c_poly, int permute) {
    const bool cf32 = (c_poly != 0) && (*flag != 0u);
    const int wave = threadIdx.x >> 6;
    const int lane = threadIdx.x & 63;
    const int l15  = lane & 15;
    const int q    = lane >> 4;
    const int m0   = blockIdx.x * 256 + wave * 64;
    const int n0   = blockIdx.y * 64;

    // permuted column base (uniform): j in [n0, n0+64) -> h=(j>>8), r=(j>>6)&3
    int colbase = n0;
    if (permute) {
        int jc = n0 >> 6;
        colbase = ((jc & 3) * 4 + (jc >> 2)) * 64;   // r*256 + h*64
    }

    floatx4 acc[4][4];
#pragma unroll
    for (int i = 0; i < 4; i++)
#pragma unroll
        for (int j = 0; j < 4; j++) acc[i][j] = (floatx4){0.f, 0.f, 0.f, 0.f};

    for (int kc = 0; kc < K; kc += 32) {
        short8 af[4], bfr[4];
#pragma unroll
        for (int mt = 0; mt < 4; mt++)
            af[mt] = *(const short8*)(A + (size_t)(m0 + mt * 16 + l15) * K + kc + q * 8);
#pragma unroll
        for (int nt = 0; nt < 4; nt++)
            bfr[nt] = *(const short8*)(B + (size_t)(n0 + nt * 16 + l15) * K + kc + q * 8);
#pragma unroll
        for (int mt = 0; mt < 4; mt++)
#pragma unroll
            for (int nt = 0; nt < 4; nt++)
                acc[mt][nt] = __builtin_amdgcn_mfma_f32_16x16x32_bf16(af[mt], bfr[nt],
                                                                     acc[mt][nt], 0, 0, 0);
    }

#pragma unroll
    for (int mt = 0; mt < 4; mt++)
#pragma unroll
        for (int nt = 0; nt < 4; nt++)
#pragma unroll
            for (int r = 0; r < 4; r++) {
                int row = m0 + mt * 16 + q * 4 + r;
                int col = colbase + nt * 16 + l15;
                if (row < M) {
                    size_t idx = (size_t)row * Nout + col;
                    float v = acc[mt][nt][r];
                    if (cf32) C32[idx] = v;
                    else      C16[idx] = (unsigned short)f2bf(v);
                }
            }
}

// ---------------------------------------------------------------------------
// per (n, c'=r*4+h): score dots.  proj rows are (n, r, h); s_src/s_trg keep
// the (n, h*4+r) indexing used by fill_k.
// ---------------------------------------------------------------------------
__global__ __launch_bounds__(256) void scores_k(const unsigned short* __restrict__ proj,
                                                const float* __restrict__ wf,
                                                float* __restrict__ s_src,
                                                float* __restrict__ s_trg, int NC) {
    int tid = blockIdx.x * 256 + threadIdx.x;
    if (tid >= NC) return;
    int cp = tid & 15;                         // r*4 + h
    int cell = ((cp & 3) * 4) + (cp >> 2);     // h*4 + r
    const uint4v* p  = (const uint4v*)(proj + (size_t)tid * 64);
    const float* av  = wf + WF_SSC + cell * 64;
    const float* bv  = wf + WF_STC + cell * 64;
    float accA = 0.f, accB = 0.f;
#pragma unroll
    for (int c = 0; c < 8; c++) {
        uint4v pv = p[c];
#pragma unroll
        for (int j = 0; j < 4; j++) {
            int k = c * 8 + j * 2;
            float p0 = bflo(pv[j]), p1 = bfhi(pv[j]);
            accA = fmaf(p0, av[k], accA);
            accA = fmaf(p1, av[k + 1], accA);
            accB = fmaf(p0, bv[k], accB);
            accB = fmaf(p1, bv[k + 1], accB);
        }
    }
    int oidx = (tid & ~15) + cell;
    s_src[oidx] = accA;
    s_trg[oidx] = accB;
}

// ---------------------------------------------------------------------------
// CSR build: count -> hierarchical scan -> fill
// ---------------------------------------------------------------------------
__global__ __launch_bounds__(256) void count_k(const int* __restrict__ trg,
                                               const int* __restrict__ rel,
                                               unsigned* __restrict__ counts, int E) {
    int e = blockIdx.x * 256 + threadIdx.x;
    if (e >= E) return;
    int g = clampi(trg[e], NNODES - 1);
    int r = clampi(rel[e], 3);
    atomicAdd(&counts[g * 4 + r], 1u);
}

__global__ __launch_bounds__(256) void scan1_k(const unsigned* __restrict__ counts,
                                               unsigned* __restrict__ offsets,
                                               unsigned* __restrict__ bsum) {
    __shared__ unsigned ts[256];
    int t = threadIdx.x;
    int base = blockIdx.x * 1024 + t * 4;
    uint4v c = {0u, 0u, 0u, 0u};
    if (base + 3 < NBINS) c = *(const uint4v*)(counts + base);
    else {
#pragma unroll
        for (int j = 0; j < 4; j++) c[j] = (base + j < NBINS) ? counts[base + j] : 0u;
    }
    ts[t] = c[0] + c[1] + c[2] + c[3];
    __syncthreads();
    for (int off = 1; off < 256; off <<= 1) {
        unsigned v = (t >= off) ? ts[t - off] : 0u;
        __syncthreads();
        ts[t] += v;
        __syncthreads();
    }
    unsigned pre = (t == 0) ? 0u : ts[t - 1];
    uint4v o;
    o[0] = pre;
    o[1] = pre + c[0];
    o[2] = pre + c[0] + c[1];
    o[3] = pre + c[0] + c[1] + c[2];
    if (base + 3 < NBINS) *(uint4v*)(offsets + base) = o;
    else {
#pragma unroll
        for (int j = 0; j < 4; j++) if (base + j < NBINS) offsets[base + j] = o[j];
    }
    if (t == 255) bsum[blockIdx.x] = ts[255];
}

__global__ __launch_bounds__(256) void scan2_k(unsigned* __restrict__ bsum,
                                               unsigned* __restrict__ offsets) {
    __shared__ unsigned ts[256];
    int t = threadIdx.x;
    unsigned v = (t < NSCANB) ? bsum[t] : 0u;
    ts[t] = v;
    __syncthreads();
    for (int off = 1; off < 256; off <<= 1) {
        unsigned u = (t >= off) ? ts[t - off] : 0u;
        __syncthreads();
        ts[t] += u;
        __syncthreads();
    }
    if (t < NSCANB) bsum[t] = (t == 0) ? 0u : ts[t - 1];
    if (t == 255) offsets[NBINS] = ts[255];
}

__global__ __launch_bounds__(256) void scan3_k(unsigned* __restrict__ offsets,
                                               unsigned* __restrict__ cursor,
                                               const unsigned* __restrict__ bsum) {
    int t = threadIdx.x;
    unsigned base = bsum[blockIdx.x];
    int idx = blockIdx.x * 1024 + t * 4;
    if (idx + 3 < NBINS) {
        uint4v o = *(const uint4v*)(offsets + idx);
        o[0] += base; o[1] += base; o[2] += base; o[3] += base;
        *(uint4v*)(offsets + idx) = o;
        *(uint4v*)(cursor + idx) = o;
    } else {
#pragma unroll
        for (int j = 0; j < 4; j++)
            if (idx + j < NBINS) {
                unsigned v = offsets[idx + j] + base;
                offsets[idx + j] = v;
                cursor[idx + j] = v;
            }
    }
}

__global__ __launch_bounds__(256) void fill_k(const int* __restrict__ src,
                                              const int* __restrict__ trg,
                                              const int* __restrict__ rel,
                                              const float* __restrict__ s_src,
                                              const float* __restrict__ s_trg,
                                              unsigned* __restrict__ cursor,
                                              unsigned* __restrict__ esrc,
                                              floatx4* __restrict__ eexp, int E) {
    int e = blockIdx.x * 256 + threadIdx.x;
    if (e >= E) return;
    int s = clampi(src[e], NNODES - 1);
    int g = clampi(trg[e], NNODES - 1);
    int r = clampi(rel[e], 3);
    unsigned pos = atomicAdd(&cursor[g * 4 + r], 1u);
    if (pos >= (unsigned)E) pos = E - 1;
    esrc[pos] = (unsigned)s;
    floatx4 v;
#pragma unroll
    for (int h = 0; h < 4; h++) {
        float val = s_src[s * 16 + h * 4 + r] + s_trg[g * 16 + h * 4 + r];
        val = val > 0.f ? val : 0.2f * val;
        v[h] = expf(val);
    }
    eexp[pos] = v;
}

// ---------------------------------------------------------------------------
// aggregation: one WAVE per bin (n,r). proj now (n, r, h, f): per edge ONE
// contiguous 512B wave load (ushort4/lane; lane = h*16+fg, covers f=fg*4..+3).
// agg layout (bin, h, f) bf16.
// ---------------------------------------------------------------------------
__global__ __launch_bounds__(256) void rowagg2_k(const unsigned* __restrict__ offsets,
                                                 const unsigned* __restrict__ esrc,
                                                 const floatx4* __restrict__ eexp,
                                                 const unsigned short* __restrict__ proj,
                                                 unsigned short* __restrict__ agg) {
    int wave = threadIdx.x >> 6, lane = threadIdx.x & 63;
    int bin = blockIdx.x * 4 + wave;
    if (bin >= NBINS) return;
    int r = bin & 3;
    int h = lane >> 4;
    unsigned beg = offsets[bin], end = offsets[bin + 1];

    float a0 = 0.f, a1 = 0.f, a2 = 0.f, a3 = 0.f, den = 0.f;
    for (unsigned i = beg; i < end; i++) {
        unsigned s = esrc[i];                 // wave-uniform (scalar load)
        floatx4 pe = eexp[i];                 // wave-uniform 16B
        float p = pe[h];
        const short4v* pp = (const short4v*)(proj + (size_t)s * 1024 + r * 256) + lane;
        short4v v = *pp;                      // 8B/lane, 512B/wave contiguous
        den += p;
        a0 = fmaf(p, bf2f((unsigned short)v[0]), a0);
        a1 = fmaf(p, bf2f((unsigned short)v[1]), a1);
        a2 = fmaf(p, bf2f((unsigned short)v[2]), a2);
        a3 = fmaf(p, bf2f((unsigned short)v[3]), a3);
    }
    float inv = 1.f / (den + 1e-16f);
    short4v o;
    o[0] = (short)f2bf(a0 * inv);
    o[1] = (short)f2bf(a1 * inv);
    o[2] = (short)f2bf(a2 * inv);
    o[3] = (short)f2bf(a3 * inv);
    *((short4v*)(agg + (size_t)bin * 256) + lane) = o;
}

// ---------------------------------------------------------------------------
// MFMA MLP (unchanged from round 6)
// ---------------------------------------------------------------------------
__global__ __launch_bounds__(256, 2) void mlp_mfma_k(const unsigned short* __restrict__ agg,
                                                     const float* __restrict__ wf,
                                                     float* __restrict__ sc) {
    __shared__ float lds[4][16 * 68];
    const int wave = threadIdx.x >> 6;
    const int lane = threadIdx.x & 63;
    const int l15 = lane & 15, q = lane >> 4;
    float* L = lds[wave];

    short8 w1f[2][4], w2f[2][4];
#pragma unroll
    for (int ks = 0; ks < 2; ks++)
#pragma unroll
        for (int nt = 0; nt < 4; nt++) {
            w1f[ks][nt] = pack_bf16(wf + WF_W1 + (nt * 16 + l15) * 64 + ks * 32 + q * 8);
            w2f[ks][nt] = pack_bf16(wf + WF_W2 + (nt * 16 + l15) * 64 + ks * 32 + q * 8);
        }
    float b1v[4], b2v[4], w3v[4];
#pragma unroll
    for (int nt = 0; nt < 4; nt++) {
        b1v[nt] = wf[WF_B1 + nt * 16 + l15];
        b2v[nt] = wf[WF_B2 + nt * 16 + l15];
        w3v[nt] = wf[WF_W3 + nt * 16 + l15];
    }
    float b3v = wf[WF_B3];

    int wave_id = blockIdx.x * 4 + wave;
#pragma unroll 1
    for (int t = 0; t < 4; t++) {
        int row0 = (wave_id * 4 + t) * 16;
        short8 a1[2];
#pragma unroll
        for (int ks = 0; ks < 2; ks++)
            a1[ks] = *(const short8*)(agg + (size_t)(row0 + l15) * 64 + ks * 32 + q * 8);
        floatx4 acc1[4];
#pragma unroll
        for (int nt = 0; nt < 4; nt++) {
            acc1[nt] = (floatx4){0.f, 0.f, 0.f, 0.f};
            acc1[nt] = __builtin_amdgcn_mfma_f32_16x16x32_bf16(a1[0], w1f[0][nt], acc1[nt], 0, 0, 0);
            acc1[nt] = __builtin_amdgcn_mfma_f32_16x16x32_bf16(a1[1], w1f[1][nt], acc1[nt], 0, 0, 0);
        }
        __syncthreads();
#pragma unroll
        for (int nt = 0; nt < 4; nt++)
#pragma unroll
            for (int rg = 0; rg < 4; rg++)
                L[(q * 4 + rg) * 68 + nt * 16 + l15] = fmaxf(acc1[nt][rg] + b1v[nt], 0.f);
        __syncthreads();
        short8 a2[2];
#pragma unroll
        for (int ks = 0; ks < 2; ks++) {
            short8 rr;
#pragma unroll
            for (int j = 0; j < 8; j++)
                rr[j] = (short)f2bf(L[l15 * 68 + ks * 32 + q * 8 + j]);
            a2[ks] = rr;
        }
        floatx4 acc2[4];
#pragma unroll
        for (int nt = 0; nt < 4; nt++) {
            acc2[nt] = (floatx4){0.f, 0.f, 0.f, 0.f};
            acc2[nt] = __builtin_amdgcn_mfma_f32_16x16x32_bf16(a2[0], w2f[0][nt], acc2[nt], 0, 0, 0);
            acc2[nt] = __builtin_amdgcn_mfma_f32_16x16x32_bf16(a2[1], w2f[1][nt], acc2[nt], 0, 0, 0);
        }
        float p[4];
#pragma unroll
        for (int rg = 0; rg < 4; rg++) {
            float s = 0.f;
#pragma unroll
            for (int nt = 0; nt < 4; nt++)
                s = fmaf(fmaxf(acc2[nt][rg] + b2v[nt], 0.f), w3v[nt], s);
            p[rg] = s;
        }
#pragma unroll
        for (int off = 1; off < 16; off <<= 1) {
#pragma unroll
            for (int rg = 0; rg < 4; rg++) p[rg] += __shfl_xor(p[rg], off);
        }
        if (l15 == 0) {
#pragma unroll
            for (int rg = 0; rg < 4; rg++) {
                float acc = p[rg] + b3v;
                float sp = fmaxf(acc, 0.f) + log1pf(expf(-fabsf(acc)));
                float m = acc * tanhf(sp);
                int s_id = row0 + q * 4 + rg;
                int n = s_id >> 4, r = (s_id >> 2) & 3, h = s_id & 3;
                sc[n * 16 + h * 4 + r] = m;
            }
        }
    }
}

// ---------------------------------------------------------------------------
// final: softmax over r, weighted sum, +skip(in d_out)+bias, ELU, LayerNorm
// ---------------------------------------------------------------------------
__global__ __launch_bounds__(256) void final_k(const unsigned short* __restrict__ agg,
                                               const float* __restrict__ sc,
                                               const float* __restrict__ wf,
                                               const unsigned* __restrict__ flag,
                                               unsigned short* __restrict__ out16,
                                               float* __restrict__ out32) {
    const bool f32 = (*flag != 0u);
    int n = blockIdx.x, t = threadIdx.x;
    int h = t >> 6, f = t & 63;
    float s0 = sc[n * 16 + h * 4 + 0];
    float s1 = sc[n * 16 + h * 4 + 1];
    float s2 = sc[n * 16 + h * 4 + 2];
    float s3 = sc[n * 16 + h * 4 + 3];
    float mx = fmaxf(fmaxf(s0, s1), fmaxf(s2, s3));
    float e0 = expf(s0 - mx), e1 = expf(s1 - mx), e2 = expf(s2 - mx), e3 = expf(s3 - mx);
    float inv = 1.f / (e0 + e1 + e2 + e3);
    size_t base = (size_t)n * 1024 + h * 64 + f;
    float a0 = bf2f(agg[base]);
    float a1 = bf2f(agg[base + 256]);
    float a2 = bf2f(agg[base + 512]);
    float a3 = bf2f(agg[base + 768]);
    float v = (e0 * a0 + e1 * a1 + e2 * a2 + e3 * a3) * inv;
    size_t oidx = (size_t)n * 256 + t;
    float skipv = f32 ? out32[oidx] : bf2f(out16[oidx]);
    v += skipv + wf[WF_BIAS + t];
    v = v > 0.f ? v : expm1f(v);

    float s = v, qq = v * v;
#pragma unroll
    for (int o = 1; o < 64; o <<= 1) {
        s += __shfl_xor(s, o);
        qq += __shfl_xor(qq, o);
    }
    __shared__ float red[8];
    __shared__ float stat[2];
    int wv = t >> 6, ln = t & 63;
    if (ln == 0) { red[wv] = s; red[4 + wv] = qq; }
    __syncthreads();
    if (t == 0) {
        float S = red[0] + red[1] + red[2] + red[3];
        float Q = red[4] + red[5] + red[6] + red[7];
        float mu = S * (1.f / 256.f);
        float var = fmaxf(Q * (1.f / 256.f) - mu * mu, 0.f);
        stat[0] = mu;
        stat[1] = rsqrtf(var + 1e-5f);
    }
    __syncthreads();
    float o = (v - stat[0]) * stat[1] * wf[WF_GAMMA + t] + wf[WF_BETA + t];
    if (f32) out32[oidx] = o;
    else     out16[oidx] = (unsigned short)f2bf(o);
}

// ---------------------------------------------------------------------------
// workspace layout (~226.85 MB). xbf overlays agg (disjoint lifetimes on the
// serial stream: xbf used only by gemms, agg written later by rowagg2).
// wpbf/wsbf overlay s_src/s_trg (written by scores_k after gemms finish).
// ---------------------------------------------------------------------------
extern "C" void kernel_launch(void* const* d_in, const int* in_sizes, int n_in,
                              void* d_out, int out_size, void* d_ws, size_t ws_size,
                              hipStream_t stream) {
    if (ws_size < 226900000) return;

    const void* x      = d_in[0];
    const int* src     = (const int*)d_in[1];
    const int* trg     = (const int*)d_in[2];
    const int* rel     = (const int*)d_in[3];
    const void* W_proj = d_in[5];
    const void* ssc    = d_in[6];
    const void* stc    = d_in[7];
    const void* W1     = d_in[8];
    const void* b1     = d_in[9];
    const void* W2     = d_in[10];
    const void* b2     = d_in[11];
    const void* W3     = d_in[12];
    const void* b3     = d_in[13];
    const void* W_skip = d_in[14];
    const void* bias   = d_in[15];
    const void* gamma  = d_in[16];
    const void* beta   = d_in[17];
    unsigned short* out16 = (unsigned short*)d_out;
    float* out32          = (float*)d_out;

    char* w = (char*)d_ws;
    unsigned short* proj = (unsigned short*)(w + 0);
    unsigned short* agg  = (unsigned short*)(w + 102400000);
    unsigned short* xbf  = (unsigned short*)(w + 102400000);  // overlay (early life)
    unsigned short* wpbf = (unsigned short*)(w + 204800000);  // overlay s_src
    unsigned short* wsbf = (unsigned short*)(w + 208000000);  // overlay s_trg
    float* s_src         = (float*)(w + 204800000);
    float* s_trg         = (float*)(w + 208000000);
    floatx4* eexp        = (floatx4*)(w + 211200000);
    unsigned* esrc       = (unsigned*)(w + 219200000);
    unsigned* counts     = (unsigned*)(w + 221200000);
    unsigned* offsets    = (unsigned*)(w + 222000000);
    unsigned* cursor     = (unsigned*)(w + 222800016);
    float* sc            = (float*)(w + 223600016);
    float* wf            = (float*)(w + 226800016);
    unsigned* flag       = (unsigned*)(w + 226844824);
    unsigned* bsum       = (unsigned*)(w + 226844832);

    hipMemsetAsync(counts, 0, NBINS * 4, stream);

    probe_k<<<1, 256, 0, stream>>>((const unsigned short*)x, flag);
    wconv_k<<<1, 1024, 0, stream>>>(W1, b1, W2, b2, W3, b3, ssc, stc, bias, gamma, beta,
                                    flag, wf);
    // bf16 canonicalization of GEMM inputs (x zero-padded to MPAD rows)
    convbf_k<<<(MPAD * 256) / (8 * 256), 256, 0, stream>>>(x, xbf, NNODES * 256,
                                                           MPAD * 256, flag);
    convbf_k<<<128, 256, 0, stream>>>(W_proj, wpbf, 1024 * 256, 1024 * 256, flag);
    convbf_k<<<32, 256, 0, stream>>>(W_skip, wsbf, 256 * 256, 256 * 256, flag);
    // proj = x @ W_proj^T, columns permuted to (r,h,f)
    gemm_bt2<<<dim3(196, 16), 256, 0, stream>>>(xbf, wpbf, proj, nullptr,
                                                NNODES, 1024, 256, flag, 0, 1);
    // skip = x @ W_skip^T -> d_out (dtype per flag)
    gemm_bt2<<<dim3(196, 4), 256, 0, stream>>>(xbf, wsbf, out16, out32,
                                               NNODES, 256, 256, flag, 1, 0);
    scores_k<<<3125, 256, 0, stream>>>(proj, wf, s_src, s_trg, NNODES * 16);
    count_k<<<1954, 256, 0, stream>>>(trg, rel, counts, NEDGES);
    scan1_k<<<NSCANB, 256, 0, stream>>>(counts, offsets, bsum);
    scan2_k<<<1, 256, 0, stream>>>(bsum, offsets);
    scan3_k<<<NSCANB, 256, 0, stream>>>(offsets, cursor, bsum);
    fill_k<<<1954, 256, 0, stream>>>(src, trg, rel, s_src, s_trg, cursor, esrc, eexp, NEDGES);
    rowagg2_k<<<NBINS / 4, 256, 0, stream>>>(offsets, esrc, eexp, proj, agg);
    mlp_mfma_k<<<3125, 256, 0, stream>>>(agg, wf, sc);
    final_k<<<NNODES, 256, 0, stream>>>(agg, sc, wf, flag, out16, out32);
}

// Round 8
// 577.502 us; speedup vs baseline: 2.6071x; 1.1426x over previous
//
#include <hip/hip_runtime.h>

#define NNODES 50000
#define NEDGES 500000
#define NBINS  (NNODES * 4)
#define NSCANB 196   // ceil(NBINS / 1024)
#define MPAD   50176 // 784*64

// wf fp32 arena offsets (in floats)
#define WF_W1    0
#define WF_B1    4096
#define WF_W2    4160
#define WF_B2    8256
#define WF_W3    8320
#define WF_B3    8384
#define WF_SSC   8385
#define WF_STC   9409
#define WF_BIAS  10433
#define WF_GAMMA 10689
#define WF_BETA  10945
#define WF_TOT   11201

typedef __attribute__((ext_vector_type(8))) short short8;
typedef __attribute__((ext_vector_type(4))) short short4v;
typedef __attribute__((ext_vector_type(4))) float floatx4;
typedef __attribute__((ext_vector_type(4))) unsigned int uint4v;

__device__ __forceinline__ float bf2f(unsigned short u) {
    return __uint_as_float(((unsigned)u) << 16);
}
__device__ __forceinline__ unsigned f2bf(float f) {
    unsigned u = __float_as_uint(f);
    u += 0x7fffu + ((u >> 16) & 1u);
    return u >> 16;
}
__device__ __forceinline__ float bflo(unsigned u) { return __uint_as_float(u << 16); }
__device__ __forceinline__ float bfhi(unsigned u) { return __uint_as_float(u & 0xffff0000u); }
__device__ __forceinline__ int clampi(int v, int hi) { return v < 0 ? 0 : (v > hi ? hi : v); }

__device__ __forceinline__ short8 pack_bf16(const float* p) {
    short8 r;
#pragma unroll
    for (int j = 0; j < 8; j++) r[j] = (short)f2bf(p[j]);
    return r;
}

// ---------------------------------------------------------------------------
// dtype probe: flag=1 means inputs are fp32
// ---------------------------------------------------------------------------
__global__ __launch_bounds__(256) void probe_k(const unsigned short* __restrict__ xs,
                                               unsigned* __restrict__ flag) {
    __shared__ unsigned cnt;
    if (threadIdx.x == 0) cnt = 0;
    __syncthreads();
    unsigned local = 0;
    for (int i = threadIdx.x; i < 8192; i += 256) {
        float v = bf2f(xs[i]);
        if (!(fabsf(v) < 1e10f)) local++;
    }
    atomicAdd(&cnt, local);
    __syncthreads();
    if (threadIdx.x == 0) *flag = (cnt > 256u) ? 1u : 0u;
}

// ---------------------------------------------------------------------------
// polymorphic small-param conversion into fp32 arena
// ---------------------------------------------------------------------------
__device__ __forceinline__ float ldf(const void* p, int i, bool f32) {
    return f32 ? ((const float*)p)[i] : bf2f(((const unsigned short*)p)[i]);
}

__global__ __launch_bounds__(1024) void wconv_k(const void* W1, const void* b1,
                                                const void* W2, const void* b2,
                                                const void* W3, const void* b3,
                                                const void* ssc, const void* stc,
                                                const void* bias, const void* gamma,
                                                const void* beta,
                                                const unsigned* __restrict__ flag,
                                                float* __restrict__ wf) {
    bool f32 = (*flag != 0u);
    for (int i = threadIdx.x; i < WF_TOT; i += 1024) {
        float v;
        if (i < WF_B1)          v = ldf(W1, i - WF_W1, f32);
        else if (i < WF_W2)     v = ldf(b1, i - WF_B1, f32);
        else if (i < WF_B2)     v = ldf(W2, i - WF_W2, f32);
        else if (i < WF_W3)     v = ldf(b2, i - WF_B2, f32);
        else if (i < WF_B3)     v = ldf(W3, i - WF_W3, f32);
        else if (i < WF_SSC)    v = ldf(b3, i - WF_B3, f32);
        else if (i < WF_STC)    v = ldf(ssc, i - WF_SSC, f32);
        else if (i < WF_BIAS)   v = ldf(stc, i - WF_STC, f32);
        else if (i < WF_GAMMA)  v = ldf(bias, i - WF_BIAS, f32);
        else if (i < WF_BETA)   v = ldf(gamma, i - WF_GAMMA, f32);
        else                    v = ldf(beta, i - WF_BETA, f32);
        wf[i] = v;
    }
}

// ---------------------------------------------------------------------------
// bulk matrix conversion (fp32|bf16 -> bf16), zero-padded to npad elems
// ---------------------------------------------------------------------------
__global__ __launch_bounds__(256) void convbf_k(const void* __restrict__ src,
                                                unsigned short* __restrict__ dst,
                                                int nelem, int npad,
                                                const unsigned* __restrict__ flag) {
    int i8 = (blockIdx.x * 256 + threadIdx.x) * 8;
    if (i8 >= npad) return;
    short8 o;
    if (i8 < nelem) {
        if (*flag) {
            const float* pf = (const float*)src + i8;
            floatx4 a = *(const floatx4*)pf;
            floatx4 b = *(const floatx4*)(pf + 4);
            o[0] = (short)f2bf(a[0]); o[1] = (short)f2bf(a[1]);
            o[2] = (short)f2bf(a[2]); o[3] = (short)f2bf(a[3]);
            o[4] = (short)f2bf(b[0]); o[5] = (short)f2bf(b[1]);
            o[6] = (short)f2bf(b[2]); o[7] = (short)f2bf(b[3]);
        } else {
            o = *(const short8*)((const unsigned short*)src + i8);
        }
    } else {
#pragma unroll
        for (int j = 0; j < 8; j++) o[j] = 0;
    }
    *(short8*)(dst + i8) = o;
}

// ---------------------------------------------------------------------------
// fused one-pass GEMM: one wave per 64 rows of x (A-stripe register-resident).
// Sweeps 16 proj column groups (writes proj in (n,r,h,f) layout + fused
// s_src/s_trg score dots) and 4 skip column groups (writes d_out).
// ---------------------------------------------------------------------------
__global__ __launch_bounds__(64) void gemm_fused_k(const unsigned short* __restrict__ A,
                                                   const unsigned short* __restrict__ Bp,
                                                   const unsigned short* __restrict__ Bs,
                                                   unsigned short* __restrict__ proj,
                                                   unsigned short* __restrict__ out16,
                                                   float* __restrict__ out32,
                                                   const float* __restrict__ wf,
                                                   float* __restrict__ s_src,
                                                   float* __restrict__ s_trg,
                                                   const unsigned* __restrict__ flag) {
    const bool cf32 = (*flag != 0u);
    const int lane = threadIdx.x & 63;
    const int l15 = lane & 15, q = lane >> 4;
    const int m0 = blockIdx.x * 64;

    // A-stripe: 64 rows x 256 K in registers (128 VGPRs)
    short8 af[4][8];
#pragma unroll
    for (int mt = 0; mt < 4; mt++)
#pragma unroll
        for (int ks = 0; ks < 8; ks++)
            af[mt][ks] = *(const short8*)(A + (size_t)(m0 + mt * 16 + l15) * 256 + ks * 32 + q * 8);

    // ---- proj columns ----
#pragma unroll 1
    for (int cg = 0; cg < 16; cg++) {
        floatx4 acc[4][4];
#pragma unroll
        for (int i = 0; i < 4; i++)
#pragma unroll
            for (int j = 0; j < 4; j++) acc[i][j] = (floatx4){0.f, 0.f, 0.f, 0.f};
#pragma unroll
        for (int ks = 0; ks < 8; ks++) {
            short8 bfr[4];
#pragma unroll
            for (int nt = 0; nt < 4; nt++)
                bfr[nt] = *(const short8*)(Bp + (size_t)(cg * 64 + nt * 16 + l15) * 256 + ks * 32 + q * 8);
#pragma unroll
            for (int mt = 0; mt < 4; mt++)
#pragma unroll
                for (int nt = 0; nt < 4; nt++)
                    acc[mt][nt] = __builtin_amdgcn_mfma_f32_16x16x32_bf16(af[mt][ks], bfr[nt],
                                                                         acc[mt][nt], 0, 0, 0);
        }
        const int h = cg >> 2, r = cg & 3;
        const int colbase = (r * 4 + h) * 64;   // (r,h,f) layout
        const int cell = h * 4 + r;             // s_src/s_trg cell index
        float sa[4], sb[4];
#pragma unroll
        for (int nt = 0; nt < 4; nt++) {
            sa[nt] = wf[WF_SSC + cell * 64 + nt * 16 + l15];
            sb[nt] = wf[WF_STC + cell * 64 + nt * 16 + l15];
        }
#pragma unroll
        for (int mt = 0; mt < 4; mt++) {
            float pa[4] = {0.f, 0.f, 0.f, 0.f};
            float pb[4] = {0.f, 0.f, 0.f, 0.f};
#pragma unroll
            for (int nt = 0; nt < 4; nt++)
#pragma unroll
                for (int rg = 0; rg < 4; rg++) {
                    int row = m0 + mt * 16 + q * 4 + rg;
                    float v = acc[mt][nt][rg];
                    unsigned short vb = (unsigned short)f2bf(v);
                    if (row < NNODES)
                        proj[(size_t)row * 1024 + colbase + nt * 16 + l15] = vb;
                    float vr = bf2f(vb);   // match prior bf16-rounded score path
                    pa[rg] = fmaf(vr, sa[nt], pa[rg]);
                    pb[rg] = fmaf(vr, sb[nt], pb[rg]);
                }
#pragma unroll
            for (int off = 1; off < 16; off <<= 1)
#pragma unroll
                for (int rg = 0; rg < 4; rg++) {
                    pa[rg] += __shfl_xor(pa[rg], off);
                    pb[rg] += __shfl_xor(pb[rg], off);
                }
            if (l15 == 0) {
#pragma unroll
                for (int rg = 0; rg < 4; rg++) {
                    int row = m0 + mt * 16 + q * 4 + rg;
                    if (row < NNODES) {
                        s_src[row * 16 + cell] = pa[rg];
                        s_trg[row * 16 + cell] = pb[rg];
                    }
                }
            }
        }
    }

    // ---- skip columns ----
#pragma unroll 1
    for (int cg = 0; cg < 4; cg++) {
        floatx4 acc[4][4];
#pragma unroll
        for (int i = 0; i < 4; i++)
#pragma unroll
            for (int j = 0; j < 4; j++) acc[i][j] = (floatx4){0.f, 0.f, 0.f, 0.f};
#pragma unroll
        for (int ks = 0; ks < 8; ks++) {
            short8 bfr[4];
#pragma unroll
            for (int nt = 0; nt < 4; nt++)
                bfr[nt] = *(const short8*)(Bs + (size_t)(cg * 64 + nt * 16 + l15) * 256 + ks * 32 + q * 8);
#pragma unroll
            for (int mt = 0; mt < 4; mt++)
#pragma unroll
                for (int nt = 0; nt < 4; nt++)
                    acc[mt][nt] = __builtin_amdgcn_mfma_f32_16x16x32_bf16(af[mt][ks], bfr[nt],
                                                                         acc[mt][nt], 0, 0, 0);
        }
#pragma unroll
        for (int mt = 0; mt < 4; mt++)
#pragma unroll
            for (int nt = 0; nt < 4; nt++)
#pragma unroll
                for (int rg = 0; rg < 4; rg++) {
                    int row = m0 + mt * 16 + q * 4 + rg;
                    if (row < NNODES) {
                        size_t idx = (size_t)row * 256 + cg * 64 + nt * 16 + l15;
                        float v = acc[mt][nt][rg];
                        if (cf32) out32[idx] = v;
                        else      out16[idx] = (unsigned short)f2bf(v);
                    }
                }
    }
}

// ---------------------------------------------------------------------------
// CSR build: count -> hierarchical scan -> fill
// ---------------------------------------------------------------------------
__global__ __launch_bounds__(256) void count_k(const int* __restrict__ trg,
                                               const int* __restrict__ rel,
                                               unsigned* __restrict__ counts, int E) {
    int e = blockIdx.x * 256 + threadIdx.x;
    if (e >= E) return;
    int g = clampi(trg[e], NNODES - 1);
    int r = clampi(rel[e], 3);
    atomicAdd(&counts[g * 4 + r], 1u);
}

__global__ __launch_bounds__(256) void scan1_k(const unsigned* __restrict__ counts,
                                               unsigned* __restrict__ offsets,
                                               unsigned* __restrict__ bsum) {
    __shared__ unsigned ts[256];
    int t = threadIdx.x;
    int base = blockIdx.x * 1024 + t * 4;
    uint4v c = {0u, 0u, 0u, 0u};
    if (base + 3 < NBINS) c = *(const uint4v*)(counts + base);
    else {
#pragma unroll
        for (int j = 0; j < 4; j++) c[j] = (base + j < NBINS) ? counts[base + j] : 0u;
    }
    ts[t] = c[0] + c[1] + c[2] + c[3];
    __syncthreads();
    for (int off = 1; off < 256; off <<= 1) {
        unsigned v = (t >= off) ? ts[t - off] : 0u;
        __syncthreads();
        ts[t] += v;
        __syncthreads();
    }
    unsigned pre = (t == 0) ? 0u : ts[t - 1];
    uint4v o;
    o[0] = pre;
    o[1] = pre + c[0];
    o[2] = pre + c[0] + c[1];
    o[3] = pre + c[0] + c[1] + c[2];
    if (base + 3 < NBINS) *(uint4v*)(offsets + base) = o;
    else {
#pragma unroll
        for (int j = 0; j < 4; j++) if (base + j < NBINS) offsets[base + j] = o[j];
    }
    if (t == 255) bsum[blockIdx.x] = ts[255];
}

__global__ __launch_bounds__(256) void scan2_k(unsigned* __restrict__ bsum,
                                               unsigned* __restrict__ offsets) {
    __shared__ unsigned ts[256];
    int t = threadIdx.x;
    unsigned v = (t < NSCANB) ? bsum[t] : 0u;
    ts[t] = v;
    __syncthreads();
    for (int off = 1; off < 256; off <<= 1) {
        unsigned u = (t >= off) ? ts[t - off] : 0u;
        __syncthreads();
        ts[t] += u;
        __syncthreads();
    }
    if (t < NSCANB) bsum[t] = (t == 0) ? 0u : ts[t - 1];
    if (t == 255) offsets[NBINS] = ts[255];
}

__global__ __launch_bounds__(256) void scan3_k(unsigned* __restrict__ offsets,
                                               unsigned* __restrict__ cursor,
                                               const unsigned* __restrict__ bsum) {
    int t = threadIdx.x;
    unsigned base = bsum[blockIdx.x];
    int idx = blockIdx.x * 1024 + t * 4;
    if (idx + 3 < NBINS) {
        uint4v o = *(const uint4v*)(offsets + idx);
        o[0] += base; o[1] += base; o[2] += base; o[3] += base;
        *(uint4v*)(offsets + idx) = o;
        *(uint4v*)(cursor + idx) = o;
    } else {
#pragma unroll
        for (int j = 0; j < 4; j++)
            if (idx + j < NBINS) {
                unsigned v = offsets[idx + j] + base;
                offsets[idx + j] = v;
                cursor[idx + j] = v;
            }
    }
}

__global__ __launch_bounds__(256) void fill_k(const int* __restrict__ src,
                                              const int* __restrict__ trg,
                                              const int* __restrict__ rel,
                                              const float* __restrict__ s_src,
                                              const float* __restrict__ s_trg,
                                              unsigned* __restrict__ cursor,
                                              unsigned* __restrict__ esrc,
                                              floatx4* __restrict__ eexp, int E) {
    int e = blockIdx.x * 256 + threadIdx.x;
    if (e >= E) return;
    int s = clampi(src[e], NNODES - 1);
    int g = clampi(trg[e], NNODES - 1);
    int r = clampi(rel[e], 3);
    unsigned pos = atomicAdd(&cursor[g * 4 + r], 1u);
    if (pos >= (unsigned)E) pos = E - 1;
    esrc[pos] = (unsigned)s;
    floatx4 v;
#pragma unroll
    for (int h = 0; h < 4; h++) {
        float val = s_src[s * 16 + h * 4 + r] + s_trg[g * 16 + h * 4 + r];
        val = val > 0.f ? val : 0.2f * val;
        v[h] = expf(val);
    }
    eexp[pos] = v;
}

// ---------------------------------------------------------------------------
// aggregation: one WAVE per bin (n,r). proj (n, r, h, f): per edge ONE
// contiguous 512B wave load. agg layout (bin, h, f) bf16.
// ---------------------------------------------------------------------------
__global__ __launch_bounds__(256) void rowagg2_k(const unsigned* __restrict__ offsets,
                                                 const unsigned* __restrict__ esrc,
                                                 const floatx4* __restrict__ eexp,
                                                 const unsigned short* __restrict__ proj,
                                                 unsigned short* __restrict__ agg) {
    int wave = threadIdx.x >> 6, lane = threadIdx.x & 63;
    int bin = blockIdx.x * 4 + wave;
    if (bin >= NBINS) return;
    int r = bin & 3;
    int h = lane >> 4;
    unsigned beg = offsets[bin], end = offsets[bin + 1];

    float a0 = 0.f, a1 = 0.f, a2 = 0.f, a3 = 0.f, den = 0.f;
    for (unsigned i = beg; i < end; i++) {
        unsigned s = esrc[i];
        floatx4 pe = eexp[i];
        float p = pe[h];
        const short4v* pp = (const short4v*)(proj + (size_t)s * 1024 + r * 256) + lane;
        short4v v = *pp;
        den += p;
        a0 = fmaf(p, bf2f((unsigned short)v[0]), a0);
        a1 = fmaf(p, bf2f((unsigned short)v[1]), a1);
        a2 = fmaf(p, bf2f((unsigned short)v[2]), a2);
        a3 = fmaf(p, bf2f((unsigned short)v[3]), a3);
    }
    float inv = 1.f / (den + 1e-16f);
    short4v o;
    o[0] = (short)f2bf(a0 * inv);
    o[1] = (short)f2bf(a1 * inv);
    o[2] = (short)f2bf(a2 * inv);
    o[3] = (short)f2bf(a3 * inv);
    *((short4v*)(agg + (size_t)bin * 256) + lane) = o;
}

// ---------------------------------------------------------------------------
// MFMA MLP
// ---------------------------------------------------------------------------
__global__ __launch_bounds__(256, 2) void mlp_mfma_k(const unsigned short* __restrict__ agg,
                                                     const float* __restrict__ wf,
                                                     float* __restrict__ sc) {
    __shared__ float lds[4][16 * 68];
    const int wave = threadIdx.x >> 6;
    const int lane = threadIdx.x & 63;
    const int l15 = lane & 15, q = lane >> 4;
    float* L = lds[wave];

    short8 w1f[2][4], w2f[2][4];
#pragma unroll
    for (int ks = 0; ks < 2; ks++)
#pragma unroll
        for (int nt = 0; nt < 4; nt++) {
            w1f[ks][nt] = pack_bf16(wf + WF_W1 + (nt * 16 + l15) * 64 + ks * 32 + q * 8);
            w2f[ks][nt] = pack_bf16(wf + WF_W2 + (nt * 16 + l15) * 64 + ks * 32 + q * 8);
        }
    float b1v[4], b2v[4], w3v[4];
#pragma unroll
    for (int nt = 0; nt < 4; nt++) {
        b1v[nt] = wf[WF_B1 + nt * 16 + l15];
        b2v[nt] = wf[WF_B2 + nt * 16 + l15];
        w3v[nt] = wf[WF_W3 + nt * 16 + l15];
    }
    float b3v = wf[WF_B3];

    int wave_id = blockIdx.x * 4 + wave;
#pragma unroll 1
    for (int t = 0; t < 4; t++) {
        int row0 = (wave_id * 4 + t) * 16;
        short8 a1[2];
#pragma unroll
        for (int ks = 0; ks < 2; ks++)
            a1[ks] = *(const short8*)(agg + (size_t)(row0 + l15) * 64 + ks * 32 + q * 8);
        floatx4 acc1[4];
#pragma unroll
        for (int nt = 0; nt < 4; nt++) {
            acc1[nt] = (floatx4){0.f, 0.f, 0.f, 0.f};
            acc1[nt] = __builtin_amdgcn_mfma_f32_16x16x32_bf16(a1[0], w1f[0][nt], acc1[nt], 0, 0, 0);
            acc1[nt] = __builtin_amdgcn_mfma_f32_16x16x32_bf16(a1[1], w1f[1][nt], acc1[nt], 0, 0, 0);
        }
        __syncthreads();
#pragma unroll
        for (int nt = 0; nt < 4; nt++)
#pragma unroll
            for (int rg = 0; rg < 4; rg++)
                L[(q * 4 + rg) * 68 + nt * 16 + l15] = fmaxf(acc1[nt][rg] + b1v[nt], 0.f);
        __syncthreads();
        short8 a2[2];
#pragma unroll
        for (int ks = 0; ks < 2; ks++) {
            short8 rr;
#pragma unroll
            for (int j = 0; j < 8; j++)
                rr[j] = (short)f2bf(L[l15 * 68 + ks * 32 + q * 8 + j]);
            a2[ks] = rr;
        }
        floatx4 acc2[4];
#pragma unroll
        for (int nt = 0; nt < 4; nt++) {
            acc2[nt] = (floatx4){0.f, 0.f, 0.f, 0.f};
            acc2[nt] = __builtin_amdgcn_mfma_f32_16x16x32_bf16(a2[0], w2f[0][nt], acc2[nt], 0, 0, 0);
            acc2[nt] = __builtin_amdgcn_mfma_f32_16x16x32_bf16(a2[1], w2f[1][nt], acc2[nt], 0, 0, 0);
        }
        float p[4];
#pragma unroll
        for (int rg = 0; rg < 4; rg++) {
            float s = 0.f;
#pragma unroll
            for (int nt = 0; nt < 4; nt++)
                s = fmaf(fmaxf(acc2[nt][rg] + b2v[nt], 0.f), w3v[nt], s);
            p[rg] = s;
        }
#pragma unroll
        for (int off = 1; off < 16; off <<= 1) {
#pragma unroll
            for (int rg = 0; rg < 4; rg++) p[rg] += __shfl_xor(p[rg], off);
        }
        if (l15 == 0) {
#pragma unroll
            for (int rg = 0; rg < 4; rg++) {
                float acc = p[rg] + b3v;
                float sp = fmaxf(acc, 0.f) + log1pf(expf(-fabsf(acc)));
                float m = acc * tanhf(sp);
                int s_id = row0 + q * 4 + rg;
                int n = s_id >> 4, r = (s_id >> 2) & 3, h = s_id & 3;
                sc[n * 16 + h * 4 + r] = m;
            }
        }
    }
}

// ---------------------------------------------------------------------------
// final: softmax over r, weighted sum, +skip(in d_out)+bias, ELU, LayerNorm
// ---------------------------------------------------------------------------
__global__ __launch_bounds__(256) void final_k(const unsigned short* __restrict__ agg,
                                               const float* __restrict__ sc,
                                               const float* __restrict__ wf,
                                               const unsigned* __restrict__ flag,
                                               unsigned short* __restrict__ out16,
                                               float* __restrict__ out32) {
    const bool f32 = (*flag != 0u);
    int n = blockIdx.x, t = threadIdx.x;
    int h = t >> 6, f = t & 63;
    float s0 = sc[n * 16 + h * 4 + 0];
    float s1 = sc[n * 16 + h * 4 + 1];
    float s2 = sc[n * 16 + h * 4 + 2];
    float s3 = sc[n * 16 + h * 4 + 3];
    float mx = fmaxf(fmaxf(s0, s1), fmaxf(s2, s3));
    float e0 = expf(s0 - mx), e1 = expf(s1 - mx), e2 = expf(s2 - mx), e3 = expf(s3 - mx);
    float inv = 1.f / (e0 + e1 + e2 + e3);
    size_t base = (size_t)n * 1024 + h * 64 + f;
    float a0 = bf2f(agg[base]);
    float a1 = bf2f(agg[base + 256]);
    float a2 = bf2f(agg[base + 512]);
    float a3 = bf2f(agg[base + 768]);
    float v = (e0 * a0 + e1 * a1 + e2 * a2 + e3 * a3) * inv;
    size_t oidx = (size_t)n * 256 + t;
    float skipv = f32 ? out32[oidx] : bf2f(out16[oidx]);
    v += skipv + wf[WF_BIAS + t];
    v = v > 0.f ? v : expm1f(v);

    float s = v, qq = v * v;
#pragma unroll
    for (int o = 1; o < 64; o <<= 1) {
        s += __shfl_xor(s, o);
        qq += __shfl_xor(qq, o);
    }
    __shared__ float red[8];
    __shared__ float stat[2];
    int wv = t >> 6, ln = t & 63;
    if (ln == 0) { red[wv] = s; red[4 + wv] = qq; }
    __syncthreads();
    if (t == 0) {
        float S = red[0] + red[1] + red[2] + red[3];
        float Q = red[4] + red[5] + red[6] + red[7];
        float mu = S * (1.f / 256.f);
        float var = fmaxf(Q * (1.f / 256.f) - mu * mu, 0.f);
        stat[0] = mu;
        stat[1] = rsqrtf(var + 1e-5f);
    }
    __syncthreads();
    float o = (v - stat[0]) * stat[1] * wf[WF_GAMMA + t] + wf[WF_BETA + t];
    if (f32) out32[oidx] = o;
    else     out16[oidx] = (unsigned short)f2bf(o);
}

// ---------------------------------------------------------------------------
// workspace layout (~226.85 MB). Overlays (serial-stream disjoint lifetimes):
//   xbf  -> agg region     (xbf read only by gemm_fused; agg written later)
//   wpbf/wsbf -> eexp head (weights read by gemm_fused; eexp written by fill_k)
// ---------------------------------------------------------------------------
extern "C" void kernel_launch(void* const* d_in, const int* in_sizes, int n_in,
                              void* d_out, int out_size, void* d_ws, size_t ws_size,
                              hipStream_t stream) {
    if (ws_size < 226900000) return;

    const void* x      = d_in[0];
    const int* src     = (const int*)d_in[1];
    const int* trg     = (const int*)d_in[2];
    const int* rel     = (const int*)d_in[3];
    const void* W_proj = d_in[5];
    const void* ssc    = d_in[6];
    const void* stc    = d_in[7];
    const void* W1     = d_in[8];
    const void* b1     = d_in[9];
    const void* W2     = d_in[10];
    const void* b2     = d_in[11];
    const void* W3     = d_in[12];
    const void* b3     = d_in[13];
    const void* W_skip = d_in[14];
    const void* bias   = d_in[15];
    const void* gamma  = d_in[16];
    const void* beta   = d_in[17];
    unsigned short* out16 = (unsigned short*)d_out;
    float* out32          = (float*)d_out;

    char* w = (char*)d_ws;
    unsigned short* proj = (unsigned short*)(w + 0);
    unsigned short* agg  = (unsigned short*)(w + 102400000);
    unsigned short* xbf  = (unsigned short*)(w + 102400000);  // overlay agg
    float* s_src         = (float*)(w + 204800000);
    float* s_trg         = (float*)(w + 208000000);
    floatx4* eexp        = (floatx4*)(w + 211200000);
    unsigned short* wpbf = (unsigned short*)(w + 211200000);  // overlay eexp head
    unsigned short* wsbf = (unsigned short*)(w + 212300000);  // overlay eexp head
    unsigned* esrc       = (unsigned*)(w + 219200000);
    unsigned* counts     = (unsigned*)(w + 221200000);
    unsigned* offsets    = (unsigned*)(w + 222000000);
    unsigned* cursor     = (unsigned*)(w + 222800016);
    float* sc            = (float*)(w + 223600016);
    float* wf            = (float*)(w + 226800016);
    unsigned* flag       = (unsigned*)(w + 226844824);
    unsigned* bsum       = (unsigned*)(w + 226844832);

    hipMemsetAsync(counts, 0, NBINS * 4, stream);

    probe_k<<<1, 256, 0, stream>>>((const unsigned short*)x, flag);
    wconv_k<<<1, 1024, 0, stream>>>(W1, b1, W2, b2, W3, b3, ssc, stc, bias, gamma, beta,
                                    flag, wf);
    convbf_k<<<(MPAD * 256) / (8 * 256), 256, 0, stream>>>(x, xbf, NNODES * 256,
                                                           MPAD * 256, flag);
    convbf_k<<<128, 256, 0, stream>>>(W_proj, wpbf, 1024 * 256, 1024 * 256, flag);
    convbf_k<<<32, 256, 0, stream>>>(W_skip, wsbf, 256 * 256, 256 * 256, flag);
    // proj + skip + score dots, one pass over A
    gemm_fused_k<<<784, 64, 0, stream>>>(xbf, wpbf, wsbf, proj, out16, out32,
                                         wf, s_src, s_trg, flag);
    count_k<<<1954, 256, 0, stream>>>(trg, rel, counts, NEDGES);
    scan1_k<<<NSCANB, 256, 0, stream>>>(counts, offsets, bsum);
    scan2_k<<<1, 256, 0, stream>>>(bsum, offsets);
    scan3_k<<<NSCANB, 256, 0, stream>>>(offsets, cursor, bsum);
    fill_k<<<1954, 256, 0, stream>>>(src, trg, rel, s_src, s_trg, cursor, esrc, eexp, NEDGES);
    rowagg2_k<<<NBINS / 4, 256, 0, stream>>>(offsets, esrc, eexp, proj, agg);
    mlp_mfma_k<<<3125, 256, 0, stream>>>(agg, wf, sc);
    final_k<<<NNODES, 256, 0, stream>>>(agg, sc, wf, flag, out16, out32);
}